// Round 1
// baseline (408.931 us; speedup 1.0000x reference)
//
#include <hip/hip_runtime.h>

#define B_  64
#define F_  64
#define NC_ 27
#define L_  1024
#define EPSV 1e-5f

static __device__ __forceinline__ float relu_(float v) { return fmaxf(v, 0.f); }

// ---------------- K1: softmax over 27 classes + 2x2 maxpool -> P[b][c][l] ----------------
__global__ void k_softmax_pool(const float* __restrict__ SP, float* __restrict__ P)
{
    int tid = blockIdx.x * 256 + threadIdx.x;       // 65536 = B * 1024
    int b = tid >> 10, ol = tid & 1023;
    int oi = ol >> 5, oj = ol & 31;
    float acc[NC_];
#pragma unroll
    for (int c = 0; c < NC_; ++c) acc[c] = 0.f;
    const float* base = SP + (size_t)b * NC_ * 4096;
#pragma unroll
    for (int p = 0; p < 4; ++p) {
        int di = p >> 1, dj = p & 1;
        int off = (2 * oi + di) * 64 + (2 * oj + dj);
        float v[NC_];
        float m = -1e30f;
#pragma unroll
        for (int c = 0; c < NC_; ++c) { v[c] = base[c * 4096 + off]; m = fmaxf(m, v[c]); }
        float s = 0.f;
#pragma unroll
        for (int c = 0; c < NC_; ++c) { v[c] = __expf(v[c] - m); s += v[c]; }
        float inv = 1.f / s;
#pragma unroll
        for (int c = 0; c < NC_; ++c) acc[c] = fmaxf(acc[c], v[c] * inv);
    }
#pragma unroll
    for (int c = 0; c < NC_; ++c)
        P[((size_t)b * NC_ + c) * L_ + ol] = acc[c];
}

// ---------------- K2: 1x1 conv (trans_w) + BN(eval) + ReLU -> y[b][f][l] ----------------
__global__ void k_trans(const float* __restrict__ x, const float* __restrict__ w,
                        const float* __restrict__ g, const float* __restrict__ beta,
                        float* __restrict__ y)
{
    __shared__ __align__(16) float sW[64 * 68];     // wT[c][f]
    const int t = threadIdx.x;
    const int b = blockIdx.x >> 2;
    const int l = ((blockIdx.x & 3) << 8) + t;
    for (int idx = t; idx < 4096; idx += 256) {
        int f = idx >> 6, c = idx & 63;
        sW[c * 68 + f] = w[idx];
    }
    __syncthreads();
    float acc[64];
#pragma unroll
    for (int f = 0; f < 64; ++f) acc[f] = 0.f;
    const float* xb = x + ((size_t)b << 16) + l;
    for (int c = 0; c < 64; ++c) {
        float xv = xb[(size_t)c * L_];
#pragma unroll
        for (int f4 = 0; f4 < 16; ++f4) {
            float4 wv = *(const float4*)&sW[c * 68 + f4 * 4];
            acc[f4 * 4 + 0] = fmaf(wv.x, xv, acc[f4 * 4 + 0]);
            acc[f4 * 4 + 1] = fmaf(wv.y, xv, acc[f4 * 4 + 1]);
            acc[f4 * 4 + 2] = fmaf(wv.z, xv, acc[f4 * 4 + 2]);
            acc[f4 * 4 + 3] = fmaf(wv.w, xv, acc[f4 * 4 + 3]);
        }
    }
    const float rs = 1.f / sqrtf(1.f + EPSV);
    float* yb = y + ((size_t)b << 16) + l;
#pragma unroll
    for (int f = 0; f < 64; ++f)
        yb[(size_t)f * L_] = relu_(g[f] * rs * acc[f] + beta[f]);
}

// ---------------- K3: yn[b][f][c] = y·w_nc^T + b_nc ; U[b][k][f] = P·y^T ----------------
__global__ void k_yn_U(const float* __restrict__ y, const float* __restrict__ P,
                       const float* __restrict__ w_nc, const float* __restrict__ b_nc,
                       float* __restrict__ yn, float* __restrict__ U)
{
    __shared__ __align__(16) float ylds[64 * 68];
    __shared__ float plds[NC_ * 68];
    const int t = threadIdx.x;                      // 512
    const int b = blockIdx.x;
    const int f = t & 63;
    const int q = t >> 6;                           // wave id 0..7 (uniform)
    const float* yb = y + ((size_t)b << 16);
    const float* Pb = P + (size_t)b * NC_ * L_;
    float pyn[4] = {0.f, 0.f, 0.f, 0.f};
    float pU[4]  = {0.f, 0.f, 0.f, 0.f};
    for (int l0 = 0; l0 < L_; l0 += 64) {
        __syncthreads();
        for (int idx = t; idx < 4096; idx += 512) {
            int ff = idx >> 6, lc = idx & 63;
            ylds[ff * 68 + lc] = yb[(size_t)ff * L_ + l0 + lc];
        }
        for (int idx = t; idx < NC_ * 64; idx += 512) {
            int c = idx >> 6, lc = idx & 63;
            plds[c * 68 + lc] = Pb[(size_t)c * L_ + l0 + lc];
        }
        __syncthreads();
#pragma unroll 4
        for (int l4 = 0; l4 < 16; ++l4) {
            float4 y4 = *(const float4*)&ylds[f * 68 + l4 * 4];
            const float ya[4] = {y4.x, y4.y, y4.z, y4.w};
#pragma unroll
            for (int r = 0; r < 4; ++r) {
                int c = q + (r << 3);
                if (c < NC_) {
#pragma unroll
                    for (int i = 0; i < 4; ++i) {
                        int l = l4 * 4 + i;
                        pyn[r] = fmaf(w_nc[(size_t)c * L_ + l0 + l], ya[i], pyn[r]);
                        pU[r]  = fmaf(plds[c * 68 + l], ya[i], pU[r]);
                    }
                }
            }
        }
    }
#pragma unroll
    for (int r = 0; r < 4; ++r) {
        int c = q + (r << 3);
        if (c < NC_) {
            yn[((size_t)b * F_ + f) * NC_ + c] = pyn[r] + b_nc[c];
            U[((size_t)b * NC_ + c) * F_ + f]  = pU[r];
        }
    }
}

// ---------------- K4: sigma[b][c][k] = yn·w_kc^T + b_kc ; Z[b][c][f] = sigma·U ----------------
__global__ void k_sigma_Z(const float* __restrict__ yn, const float* __restrict__ U,
                          const float* __restrict__ w_kc, const float* __restrict__ b_kc,
                          float* __restrict__ Z)
{
    __shared__ float syn[F_ * NC_];     // [f][c]
    __shared__ float su[NC_ * F_];      // [k][f]
    __shared__ float swk[NC_ * F_];     // [k][f]
    __shared__ float ssig[NC_ * NC_];   // [c][k]
    const int t = threadIdx.x;          // 256
    const int b = blockIdx.x;
    for (int idx = t; idx < NC_ * F_; idx += 256) {
        syn[idx] = yn[(size_t)b * F_ * NC_ + idx];
        su[idx]  = U[(size_t)b * NC_ * F_ + idx];
        swk[idx] = w_kc[idx];
    }
    __syncthreads();
    for (int idx = t; idx < NC_ * NC_; idx += 256) {
        int c = idx / NC_, k = idx - c * NC_;
        float s = b_kc[k];
        for (int ff = 0; ff < F_; ++ff)
            s = fmaf(syn[ff * NC_ + c], swk[k * F_ + ff], s);
        ssig[c * NC_ + k] = s;
    }
    __syncthreads();
    for (int idx = t; idx < NC_ * F_; idx += 256) {
        int c = idx >> 6, ff = idx & 63;
        float s = 0.f;
        for (int k = 0; k < NC_; ++k)
            s = fmaf(ssig[c * NC_ + k], su[k * F_ + ff], s);
        Z[(size_t)b * NC_ * F_ + idx] = s;
    }
}

// ---------------- K5: fused AY, GNN1, adj-GEMM, GNN2, residuals -> pre[b][l][f] ----------------
__global__ __launch_bounds__(256, 3) void k_fused(
    const float* __restrict__ P, const float* __restrict__ Zb,
    const float* __restrict__ y, const float* __restrict__ adj,
    const float* __restrict__ w_g, const float* __restrict__ b_g,
    const float* __restrict__ w_sp, const float* __restrict__ b_sp,
    float* __restrict__ pre)
{
    __shared__ __align__(16) float sA[64 * 68];
    __shared__ __align__(16) float sB[64 * 68];
    __shared__ __align__(16) float sM[64 * 68];
    const int t  = threadIdx.x;
    const int b  = blockIdx.x >> 4;
    const int l0 = (blockIdx.x & 15) << 6;
    const int lq = (t & 15) << 2;
    const int fq = (t >> 4) << 2;
    const float* yb = y + ((size_t)b << 16);

    // stage P tile + Z
    for (int idx = t; idx < NC_ * 64; idx += 256) {
        int c = idx >> 6, e = idx & 63;
        sA[c * 68 + e] = P[((size_t)b * NC_ + c) * L_ + l0 + e];
        sB[c * 68 + e] = Zb[((size_t)b * NC_ + c) * F_ + e];
    }
    __syncthreads();

    // phase A: M1[l][f] = sum_c P[c][l] * Z[c][f]
    float acc[4][4];
#pragma unroll
    for (int i = 0; i < 4; ++i)
#pragma unroll
        for (int j = 0; j < 4; ++j) acc[i][j] = 0.f;
#pragma unroll 1
    for (int c = 0; c < NC_; ++c) {
        float4 A4 = *(const float4*)&sA[c * 68 + lq];
        float4 B4 = *(const float4*)&sB[c * 68 + fq];
        const float av[4] = {A4.x, A4.y, A4.z, A4.w};
        const float bv[4] = {B4.x, B4.y, B4.z, B4.w};
#pragma unroll
        for (int i = 0; i < 4; ++i)
#pragma unroll
            for (int j = 0; j < 4; ++j) acc[i][j] = fmaf(av[i], bv[j], acc[i][j]);
    }
    __syncthreads();
    // write M1T[f][l]; load wgT[f'][f]
#pragma unroll
    for (int j = 0; j < 4; ++j)
        *(float4*)&sM[(fq + j) * 68 + lq] = make_float4(acc[0][j], acc[1][j], acc[2][j], acc[3][j]);
    for (int idx = t; idx < 4096; idx += 256) {
        int f = idx >> 6, fp = idx & 63;
        sA[fp * 68 + f] = w_g[idx];
    }
    __syncthreads();

    // phase C1: accG[l][f] = sum_f' M1[l][f'] * w_g[f][f']
    float accG[4][4];
#pragma unroll
    for (int i = 0; i < 4; ++i)
#pragma unroll
        for (int j = 0; j < 4; ++j) accG[i][j] = 0.f;
#pragma unroll 2
    for (int fp = 0; fp < 64; ++fp) {
        float4 M4 = *(const float4*)&sM[fp * 68 + lq];
        float4 W4 = *(const float4*)&sA[fp * 68 + fq];
        const float av[4] = {M4.x, M4.y, M4.z, M4.w};
        const float bv[4] = {W4.x, W4.y, W4.z, W4.w};
#pragma unroll
        for (int i = 0; i < 4; ++i)
#pragma unroll
            for (int j = 0; j < 4; ++j) accG[i][j] = fmaf(av[i], bv[j], accG[i][j]);
    }

    // phase B: G[l][f] = sum_m adj[l][m] * y[f][m]  (reuse acc)
#pragma unroll
    for (int i = 0; i < 4; ++i)
#pragma unroll
        for (int j = 0; j < 4; ++j) acc[i][j] = 0.f;
    for (int m0 = 0; m0 < L_; m0 += 64) {
        __syncthreads();
        for (int idx = t; idx < 4096; idx += 256) {
            int r = idx >> 6, mc = idx & 63;
            sA[mc * 68 + r] = adj[(size_t)(l0 + r) * L_ + m0 + mc];
        }
        for (int idx = t; idx < 4096; idx += 256) {
            int f = idx >> 6, mc = idx & 63;
            sB[mc * 68 + f] = yb[(size_t)f * L_ + m0 + mc];
        }
        __syncthreads();
#pragma unroll 4
        for (int m = 0; m < 64; ++m) {
            float4 A4 = *(const float4*)&sA[m * 68 + lq];
            float4 B4 = *(const float4*)&sB[m * 68 + fq];
            const float av[4] = {A4.x, A4.y, A4.z, A4.w};
            const float bv[4] = {B4.x, B4.y, B4.z, B4.w};
#pragma unroll
            for (int i = 0; i < 4; ++i)
#pragma unroll
                for (int j = 0; j < 4; ++j) acc[i][j] = fmaf(av[i], bv[j], acc[i][j]);
        }
    }
    __syncthreads();
    // write GT[f][l]; load wspT[f'][f]
#pragma unroll
    for (int j = 0; j < 4; ++j)
        *(float4*)&sM[(fq + j) * 68 + lq] = make_float4(acc[0][j], acc[1][j], acc[2][j], acc[3][j]);
    for (int idx = t; idx < 4096; idx += 256) {
        int f = idx >> 6, fp = idx & 63;
        sA[fp * 68 + f] = w_sp[idx];
    }
    __syncthreads();

    // phase C2: accS[l][f] = sum_f' G[l][f'] * w_sp[f][f']
    float accS[4][4];
#pragma unroll
    for (int i = 0; i < 4; ++i)
#pragma unroll
        for (int j = 0; j < 4; ++j) accS[i][j] = 0.f;
#pragma unroll 2
    for (int fp = 0; fp < 64; ++fp) {
        float4 M4 = *(const float4*)&sM[fp * 68 + lq];
        float4 W4 = *(const float4*)&sA[fp * 68 + fq];
        const float av[4] = {M4.x, M4.y, M4.z, M4.w};
        const float bv[4] = {W4.x, W4.y, W4.z, W4.w};
#pragma unroll
        for (int i = 0; i < 4; ++i)
#pragma unroll
            for (int j = 0; j < 4; ++j) accS[i][j] = fmaf(av[i], bv[j], accS[i][j]);
    }

    // epilogue: pre = relu(accG + b_g) + relu(accS + b_sp) + 3*y
    float outv[4][4];
#pragma unroll
    for (int j = 0; j < 4; ++j) {
        float bg = b_g[fq + j], bs = b_sp[fq + j];
        float4 y4 = *(const float4*)&yb[(size_t)(fq + j) * L_ + l0 + lq];
        const float ya[4] = {y4.x, y4.y, y4.z, y4.w};
#pragma unroll
        for (int i = 0; i < 4; ++i)
            outv[i][j] = relu_(accG[i][j] + bg) + relu_(accS[i][j] + bs) + 3.f * ya[i];
    }
#pragma unroll
    for (int i = 0; i < 4; ++i)
        *(float4*)&pre[((size_t)b * L_ + l0 + lq + i) * F_ + fq] =
            make_float4(outv[i][0], outv[i][1], outv[i][2], outv[i][3]);
}

// ---------------- K6: back 1x1 conv + BN(eval) + ReLU -> out[b][o][l] ----------------
__global__ void k_back(const float* __restrict__ pre, const float* __restrict__ bw,
                       const float* __restrict__ g2, const float* __restrict__ b2,
                       float* __restrict__ out)
{
    int tid = blockIdx.x * 256 + threadIdx.x;   // 65536
    int b = tid >> 10, l = tid & 1023;
    float pv[64];
    const float* pr = pre + (size_t)tid * 64;
#pragma unroll
    for (int f4 = 0; f4 < 16; ++f4) {
        float4 v = *(const float4*)&pr[f4 * 4];
        pv[f4 * 4 + 0] = v.x; pv[f4 * 4 + 1] = v.y;
        pv[f4 * 4 + 2] = v.z; pv[f4 * 4 + 3] = v.w;
    }
    const float rs = 1.f / sqrtf(1.f + EPSV);
    float* ob = out + ((size_t)b << 16) + l;
    for (int o = 0; o < 64; ++o) {
        float s = 0.f;
#pragma unroll
        for (int f = 0; f < 64; ++f)
            s = fmaf(bw[o * 64 + f], pv[f], s);
        ob[(size_t)o * L_] = relu_(g2[o] * rs * s + b2[o]);
    }
}

extern "C" void kernel_launch(void* const* d_in, const int* in_sizes, int n_in,
                              void* d_out, int out_size, void* d_ws, size_t ws_size,
                              hipStream_t stream)
{
    const float* x       = (const float*)d_in[0];
    const float* SP      = (const float*)d_in[1];
    const float* trans_w = (const float*)d_in[2];
    const float* bn1_g   = (const float*)d_in[3];
    const float* bn1_b   = (const float*)d_in[4];
    const float* w_nc    = (const float*)d_in[5];
    const float* b_nc    = (const float*)d_in[6];
    const float* w_kc    = (const float*)d_in[7];
    const float* b_kc    = (const float*)d_in[8];
    const float* w_g     = (const float*)d_in[9];
    const float* b_g     = (const float*)d_in[10];
    const float* adj     = (const float*)d_in[11];
    const float* w_sp    = (const float*)d_in[12];
    const float* b_sp    = (const float*)d_in[13];
    const float* back_w  = (const float*)d_in[14];
    const float* bn2_g   = (const float*)d_in[15];
    const float* bn2_b   = (const float*)d_in[16];
    float* out = (float*)d_out;

    float* ws  = (float*)d_ws;
    float* P   = ws;                                   // [64][27][1024]
    float* y   = P  + (size_t)B_ * NC_ * L_;           // [64][64][1024]
    float* yn  = y  + (size_t)B_ * F_ * L_;            // [64][64][27]
    float* U   = yn + (size_t)B_ * F_ * NC_;           // [64][27][64]
    float* Z   = U  + (size_t)B_ * NC_ * F_;           // [64][27][64]
    float* pre = Z  + (size_t)B_ * NC_ * F_;           // [64][1024][64]

    k_softmax_pool<<<256, 256, 0, stream>>>(SP, P);
    k_trans<<<256, 256, 0, stream>>>(x, trans_w, bn1_g, bn1_b, y);
    k_yn_U<<<64, 512, 0, stream>>>(y, P, w_nc, b_nc, yn, U);
    k_sigma_Z<<<64, 256, 0, stream>>>(yn, U, w_kc, b_kc, Z);
    k_fused<<<1024, 256, 0, stream>>>(P, Z, y, adj, w_g, b_g, w_sp, b_sp, pre);
    k_back<<<256, 256, 0, stream>>>(pre, back_w, bn2_g, bn2_b, out);
}

// Round 2
// 290.107 us; speedup vs baseline: 1.4096x; 1.4096x over previous
//
#include <hip/hip_runtime.h>

#define B_  64
#define F_  64
#define NC_ 27
#define L_  1024
#define EPSV 1e-5f

typedef __bf16 bf16x8 __attribute__((ext_vector_type(8)));
typedef float  f32x4  __attribute__((ext_vector_type(4)));

static __device__ __forceinline__ float relu_(float v) { return fmaxf(v, 0.f); }
static __device__ __forceinline__ ushort f2bf(float f) {
    __bf16 h = (__bf16)f;
    ushort r;
    __builtin_memcpy(&r, &h, 2);
    return r;
}

// ---------------- K0: convert adj -> bf16; back_w*bn2_scale -> bf16 ----------------
__global__ void k_prep(const float* __restrict__ adj, const float* __restrict__ bw,
                       const float* __restrict__ g2, ushort* __restrict__ adjb,
                       ushort* __restrict__ bwb)
{
    int blk = blockIdx.x, t = threadIdx.x;
    if (blk < 1024) {
        int i = (blk * 256 + t) * 4;
        float4 v = *(const float4*)(adj + i);
        ushort4 o;
        o.x = f2bf(v.x); o.y = f2bf(v.y); o.z = f2bf(v.z); o.w = f2bf(v.w);
        *(ushort4*)(adjb + i) = o;
    } else {
        const float rs = 1.f / sqrtf(1.f + EPSV);
        for (int j = t; j < 4096; j += 256) {
            int o = j >> 6;
            bwb[j] = f2bf(bw[j] * g2[o] * rs);
        }
    }
}

// ---------------- K1: softmax over 27 classes + 2x2 maxpool -> P fp32, Pt bf16 ----------------
__global__ void k_softmax_pool(const float* __restrict__ SP, float* __restrict__ P,
                               ushort* __restrict__ Pt)
{
    int tid = blockIdx.x * 256 + threadIdx.x;       // 65536 = B * 1024
    int b = tid >> 10, ol = tid & 1023;
    int oi = ol >> 5, oj = ol & 31;
    float acc[NC_];
#pragma unroll
    for (int c = 0; c < NC_; ++c) acc[c] = 0.f;
    const float* base = SP + (size_t)b * NC_ * 4096;
#pragma unroll
    for (int p = 0; p < 4; ++p) {
        int di = p >> 1, dj = p & 1;
        int off = (2 * oi + di) * 64 + (2 * oj + dj);
        float v[NC_];
        float m = -1e30f;
#pragma unroll
        for (int c = 0; c < NC_; ++c) { v[c] = base[c * 4096 + off]; m = fmaxf(m, v[c]); }
        float s = 0.f;
#pragma unroll
        for (int c = 0; c < NC_; ++c) { v[c] = __expf(v[c] - m); s += v[c]; }
        float inv = 1.f / s;
#pragma unroll
        for (int c = 0; c < NC_; ++c) acc[c] = fmaxf(acc[c], v[c] * inv);
    }
#pragma unroll
    for (int c = 0; c < NC_; ++c)
        P[((size_t)b * NC_ + c) * L_ + ol] = acc[c];
    // transposed bf16 copy, K padded to 32 with zeros: Pt[b][l][c]
    ushort h[32];
#pragma unroll
    for (int c = 0; c < NC_; ++c) h[c] = f2bf(acc[c]);
#pragma unroll
    for (int c = NC_; c < 32; ++c) h[c] = 0;
    ushort* pt = Pt + ((size_t)b * L_ + ol) * 32;
#pragma unroll
    for (int c0 = 0; c0 < 32; c0 += 4)
        *(ushort4*)&pt[c0] = *(ushort4*)&h[c0];
}

// ---------------- K2: 1x1 conv + BN + ReLU -> y fp32 ; yw = y^T @ w_sp^T -> bf16 ----------------
__global__ void k_trans(const float* __restrict__ x, const float* __restrict__ w,
                        const float* __restrict__ g, const float* __restrict__ beta,
                        const float* __restrict__ w_sp,
                        float* __restrict__ y, ushort* __restrict__ ywb)
{
    __shared__ __align__(16) float sW[64 * 68];     // trans_w^T [c][f]
    __shared__ __align__(16) float sS[64 * 68];     // w_sp^T    [f'][f]
    const int t = threadIdx.x;
    const int b = blockIdx.x >> 2;
    const int l = ((blockIdx.x & 3) << 8) + t;
    for (int idx = t; idx < 4096; idx += 256) {
        int f = idx >> 6, c = idx & 63;
        sW[c * 68 + f] = w[idx];
        sS[c * 68 + f] = w_sp[idx];
    }
    __syncthreads();
    float acc[64];
#pragma unroll
    for (int f = 0; f < 64; ++f) acc[f] = 0.f;
    const float* xb = x + ((size_t)b << 16) + l;
    for (int c = 0; c < 64; ++c) {
        float xv = xb[(size_t)c * L_];
#pragma unroll
        for (int f4 = 0; f4 < 16; ++f4) {
            float4 wv = *(const float4*)&sW[c * 68 + f4 * 4];
            acc[f4 * 4 + 0] = fmaf(wv.x, xv, acc[f4 * 4 + 0]);
            acc[f4 * 4 + 1] = fmaf(wv.y, xv, acc[f4 * 4 + 1]);
            acc[f4 * 4 + 2] = fmaf(wv.z, xv, acc[f4 * 4 + 2]);
            acc[f4 * 4 + 3] = fmaf(wv.w, xv, acc[f4 * 4 + 3]);
        }
    }
    const float rs = 1.f / sqrtf(1.f + EPSV);
    float* yb = y + ((size_t)b << 16) + l;
#pragma unroll
    for (int f = 0; f < 64; ++f) {
        acc[f] = relu_(g[f] * rs * acc[f] + beta[f]);
        yb[(size_t)f * L_] = acc[f];
    }
    // yw[f] = sum_f' acc[f'] * w_sp[f][f']
    float yw[64];
#pragma unroll
    for (int f = 0; f < 64; ++f) yw[f] = 0.f;
    for (int fp = 0; fp < 64; ++fp) {
        float v = acc[fp];
#pragma unroll
        for (int f4 = 0; f4 < 16; ++f4) {
            float4 w4 = *(const float4*)&sS[fp * 68 + f4 * 4];
            yw[f4 * 4 + 0] = fmaf(w4.x, v, yw[f4 * 4 + 0]);
            yw[f4 * 4 + 1] = fmaf(w4.y, v, yw[f4 * 4 + 1]);
            yw[f4 * 4 + 2] = fmaf(w4.z, v, yw[f4 * 4 + 2]);
            yw[f4 * 4 + 3] = fmaf(w4.w, v, yw[f4 * 4 + 3]);
        }
    }
    ushort* yp = ywb + ((size_t)b << 16) + l;
#pragma unroll
    for (int f = 0; f < 64; ++f)
        yp[(size_t)f * L_] = f2bf(yw[f]);
}

// ---------------- K3: yn[b][f][c] = y·w_nc^T + b_nc ; U[b][k][f] = P·y^T ----------------
__global__ void k_yn_U(const float* __restrict__ y, const float* __restrict__ P,
                       const float* __restrict__ w_nc, const float* __restrict__ b_nc,
                       float* __restrict__ yn, float* __restrict__ U)
{
    __shared__ __align__(16) float ylds[64 * 68];
    __shared__ float plds[NC_ * 68];
    const int t = threadIdx.x;                      // 512
    const int b = blockIdx.x;
    const int f = t & 63;
    const int q = t >> 6;
    const float* yb = y + ((size_t)b << 16);
    const float* Pb = P + (size_t)b * NC_ * L_;
    float pyn[4] = {0.f, 0.f, 0.f, 0.f};
    float pU[4]  = {0.f, 0.f, 0.f, 0.f};
    for (int l0 = 0; l0 < L_; l0 += 64) {
        __syncthreads();
        for (int idx = t; idx < 4096; idx += 512) {
            int ff = idx >> 6, lc = idx & 63;
            ylds[ff * 68 + lc] = yb[(size_t)ff * L_ + l0 + lc];
        }
        for (int idx = t; idx < NC_ * 64; idx += 512) {
            int c = idx >> 6, lc = idx & 63;
            plds[c * 68 + lc] = Pb[(size_t)c * L_ + l0 + lc];
        }
        __syncthreads();
#pragma unroll 4
        for (int l4 = 0; l4 < 16; ++l4) {
            float4 y4 = *(const float4*)&ylds[f * 68 + l4 * 4];
            const float ya[4] = {y4.x, y4.y, y4.z, y4.w};
#pragma unroll
            for (int r = 0; r < 4; ++r) {
                int c = q + (r << 3);
                if (c < NC_) {
#pragma unroll
                    for (int i = 0; i < 4; ++i) {
                        int l = l4 * 4 + i;
                        pyn[r] = fmaf(w_nc[(size_t)c * L_ + l0 + l], ya[i], pyn[r]);
                        pU[r]  = fmaf(plds[c * 68 + l], ya[i], pU[r]);
                    }
                }
            }
        }
    }
#pragma unroll
    for (int r = 0; r < 4; ++r) {
        int c = q + (r << 3);
        if (c < NC_) {
            yn[((size_t)b * F_ + f) * NC_ + c] = pyn[r] + b_nc[c];
            U[((size_t)b * NC_ + c) * F_ + f]  = pU[r];
        }
    }
}

// ---------------- K4: sigma = yn·w_kc^T + b_kc ; Z = sigma·U ; Zwt[f][c] = (Z·w_g^T)^T bf16 ----------------
__global__ void k_sigma_Z(const float* __restrict__ yn, const float* __restrict__ U,
                          const float* __restrict__ w_kc, const float* __restrict__ b_kc,
                          const float* __restrict__ w_g, ushort* __restrict__ Zwt)
{
    __shared__ float syn[F_ * NC_];     // [f][c]
    __shared__ float su[NC_ * F_];      // [k][f]
    __shared__ float swk[NC_ * F_];     // [k][f]
    __shared__ float ssig[NC_ * NC_];   // [c][k]
    __shared__ float sz[NC_ * F_];      // Z [c][f]
    __shared__ float swg[F_ * F_];      // w_g [f][f']
    const int t = threadIdx.x;          // 256
    const int b = blockIdx.x;
    for (int idx = t; idx < NC_ * F_; idx += 256) {
        syn[idx] = yn[(size_t)b * F_ * NC_ + idx];
        su[idx]  = U[(size_t)b * NC_ * F_ + idx];
        swk[idx] = w_kc[idx];
    }
    for (int idx = t; idx < F_ * F_; idx += 256) swg[idx] = w_g[idx];
    __syncthreads();
    for (int idx = t; idx < NC_ * NC_; idx += 256) {
        int c = idx / NC_, k = idx - c * NC_;
        float s = b_kc[k];
        for (int ff = 0; ff < F_; ++ff)
            s = fmaf(syn[ff * NC_ + c], swk[k * F_ + ff], s);
        ssig[c * NC_ + k] = s;
    }
    __syncthreads();
    for (int idx = t; idx < NC_ * F_; idx += 256) {
        int c = idx >> 6, ff = idx & 63;
        float s = 0.f;
        for (int k = 0; k < NC_; ++k)
            s = fmaf(ssig[c * NC_ + k], su[k * F_ + ff], s);
        sz[idx] = s;
    }
    __syncthreads();
    // Zw[c][f] = sum_f' Z[c][f'] * w_g[f][f'] ; store transposed [f][c], c padded to 32
    for (int idx = t; idx < F_ * 32; idx += 256) {
        int f = idx >> 5, c = idx & 31;
        float s = 0.f;
        if (c < NC_)
            for (int fp = 0; fp < F_; ++fp)
                s = fmaf(sz[c * F_ + fp], swg[f * F_ + fp], s);
        Zwt[(size_t)b * F_ * 32 + idx] = f2bf(s);
    }
}

// ---------------- K5: MFMA fused: S=adj·yw^T (K=1024), D=Pt·Zwt^T (K=32), epilogue, back conv ----------------
__global__ __launch_bounds__(256) void k_fused2(
    const ushort* __restrict__ adjb_, const ushort* __restrict__ ywb_,
    const ushort* __restrict__ Pt_, const ushort* __restrict__ Zwt_,
    const float* __restrict__ y, const float* __restrict__ b_g,
    const float* __restrict__ b_sp, const ushort* __restrict__ bwb_,
    const float* __restrict__ bn2b, float* __restrict__ out)
{
    __shared__ float sPre[4 * 32 * 68];
    const int t = threadIdx.x;
    const int w = t >> 6, lane = t & 63;
    const int rA = lane & 15, kg = lane >> 4;
    const int b = blockIdx.x >> 3;
    const int l0 = (blockIdx.x & 7) << 7;           // 128-row tile
    const int wl0 = l0 + w * 32;                    // this wave's 32 rows

    const __bf16* adjb = (const __bf16*)adjb_;
    const __bf16* ywb  = (const __bf16*)ywb_ + ((size_t)b << 16);
    const __bf16* Ptb  = (const __bf16*)Pt_  + ((size_t)b << 15);
    const __bf16* Zwtb = (const __bf16*)Zwt_ + ((size_t)b << 11);
    const __bf16* bwb  = (const __bf16*)bwb_;

    f32x4 accS[2][4], accD[2][4];
#pragma unroll
    for (int i = 0; i < 2; ++i)
#pragma unroll
        for (int j = 0; j < 4; ++j) {
            accS[i][j] = (f32x4){0.f, 0.f, 0.f, 0.f};
            accD[i][j] = (f32x4){0.f, 0.f, 0.f, 0.f};
        }

    // main GEMM: S[l][f] = sum_m adj[l][m] * yw[f][m]
    const __bf16* pa = adjb + (size_t)(wl0 + rA) * 1024 + kg * 8;
    const __bf16* pb = ywb + (size_t)rA * 1024 + kg * 8;
#pragma unroll 4
    for (int ks = 0; ks < 32; ++ks) {
        bf16x8 a0 = *(const bf16x8*)(pa + ks * 32);
        bf16x8 a1 = *(const bf16x8*)(pa + 16 * 1024 + ks * 32);
        bf16x8 f0 = *(const bf16x8*)(pb + 0 * 16384 + ks * 32);
        bf16x8 f1 = *(const bf16x8*)(pb + 1 * 16384 + ks * 32);
        bf16x8 f2 = *(const bf16x8*)(pb + 2 * 16384 + ks * 32);
        bf16x8 f3 = *(const bf16x8*)(pb + 3 * 16384 + ks * 32);
        accS[0][0] = __builtin_amdgcn_mfma_f32_16x16x32_bf16(a0, f0, accS[0][0], 0, 0, 0);
        accS[0][1] = __builtin_amdgcn_mfma_f32_16x16x32_bf16(a0, f1, accS[0][1], 0, 0, 0);
        accS[0][2] = __builtin_amdgcn_mfma_f32_16x16x32_bf16(a0, f2, accS[0][2], 0, 0, 0);
        accS[0][3] = __builtin_amdgcn_mfma_f32_16x16x32_bf16(a0, f3, accS[0][3], 0, 0, 0);
        accS[1][0] = __builtin_amdgcn_mfma_f32_16x16x32_bf16(a1, f0, accS[1][0], 0, 0, 0);
        accS[1][1] = __builtin_amdgcn_mfma_f32_16x16x32_bf16(a1, f1, accS[1][1], 0, 0, 0);
        accS[1][2] = __builtin_amdgcn_mfma_f32_16x16x32_bf16(a1, f2, accS[1][2], 0, 0, 0);
        accS[1][3] = __builtin_amdgcn_mfma_f32_16x16x32_bf16(a1, f3, accS[1][3], 0, 0, 0);
    }

    // dynamic path: D[l][f] = sum_c Pt[l][c] * Zwt[f][c], K=32 (c padded)
    {
        const __bf16* qa = Ptb + (size_t)(wl0 + rA) * 32 + kg * 8;
        bf16x8 a0 = *(const bf16x8*)(qa);
        bf16x8 a1 = *(const bf16x8*)(qa + 16 * 32);
        const __bf16* qb = Zwtb + (size_t)rA * 32 + kg * 8;
        bf16x8 z0 = *(const bf16x8*)(qb + 0 * 512);
        bf16x8 z1 = *(const bf16x8*)(qb + 1 * 512);
        bf16x8 z2 = *(const bf16x8*)(qb + 2 * 512);
        bf16x8 z3 = *(const bf16x8*)(qb + 3 * 512);
        accD[0][0] = __builtin_amdgcn_mfma_f32_16x16x32_bf16(a0, z0, accD[0][0], 0, 0, 0);
        accD[0][1] = __builtin_amdgcn_mfma_f32_16x16x32_bf16(a0, z1, accD[0][1], 0, 0, 0);
        accD[0][2] = __builtin_amdgcn_mfma_f32_16x16x32_bf16(a0, z2, accD[0][2], 0, 0, 0);
        accD[0][3] = __builtin_amdgcn_mfma_f32_16x16x32_bf16(a0, z3, accD[0][3], 0, 0, 0);
        accD[1][0] = __builtin_amdgcn_mfma_f32_16x16x32_bf16(a1, z0, accD[1][0], 0, 0, 0);
        accD[1][1] = __builtin_amdgcn_mfma_f32_16x16x32_bf16(a1, z1, accD[1][1], 0, 0, 0);
        accD[1][2] = __builtin_amdgcn_mfma_f32_16x16x32_bf16(a1, z2, accD[1][2], 0, 0, 0);
        accD[1][3] = __builtin_amdgcn_mfma_f32_16x16x32_bf16(a1, z3, accD[1][3], 0, 0, 0);
    }

    // epilogue: pre = relu(D + b_g) + relu(S + b_sp) + 3*y  -> LDS (fp32, pad 68)
    float bg4[4], bs4[4];
#pragma unroll
    for (int fc = 0; fc < 4; ++fc) { bg4[fc] = b_g[fc * 16 + rA]; bs4[fc] = b_sp[fc * 16 + rA]; }
    const float* yb = y + ((size_t)b << 16);
    const int wOff = w * 32 * 68;
#pragma unroll
    for (int lt = 0; lt < 2; ++lt) {
        int lbase = wl0 + lt * 16 + kg * 4;
        int row = lt * 16 + kg * 4;
#pragma unroll
        for (int fc = 0; fc < 4; ++fc) {
            int f = fc * 16 + rA;
            float4 yv = *(const float4*)(yb + (size_t)f * 1024 + lbase);
            f32x4 s = accS[lt][fc], d = accD[lt][fc];
            sPre[wOff + (row + 0) * 68 + f] = relu_(d[0] + bg4[fc]) + relu_(s[0] + bs4[fc]) + 3.f * yv.x;
            sPre[wOff + (row + 1) * 68 + f] = relu_(d[1] + bg4[fc]) + relu_(s[1] + bs4[fc]) + 3.f * yv.y;
            sPre[wOff + (row + 2) * 68 + f] = relu_(d[2] + bg4[fc]) + relu_(s[2] + bs4[fc]) + 3.f * yv.z;
            sPre[wOff + (row + 3) * 68 + f] = relu_(d[3] + bg4[fc]) + relu_(s[3] + bs4[fc]) + 3.f * yv.w;
        }
    }
    __syncthreads();

    // back conv: out[o][l] = relu( sum_f pre[l][f] * bwb[o][f] + bn2b[o] )
    f32x4 accO[2][4];
#pragma unroll
    for (int i = 0; i < 2; ++i)
#pragma unroll
        for (int j = 0; j < 4; ++j) accO[i][j] = (f32x4){0.f, 0.f, 0.f, 0.f};
#pragma unroll
    for (int kh = 0; kh < 2; ++kh) {
        bf16x8 af[2];
#pragma unroll
        for (int lt = 0; lt < 2; ++lt) {
            int off = wOff + (lt * 16 + rA) * 68 + kh * 32 + kg * 8;
            float4 u0 = *(const float4*)&sPre[off];
            float4 u1 = *(const float4*)&sPre[off + 4];
            bf16x8 a;
            a[0] = (__bf16)u0.x; a[1] = (__bf16)u0.y; a[2] = (__bf16)u0.z; a[3] = (__bf16)u0.w;
            a[4] = (__bf16)u1.x; a[5] = (__bf16)u1.y; a[6] = (__bf16)u1.z; a[7] = (__bf16)u1.w;
            af[lt] = a;
        }
#pragma unroll
        for (int oc = 0; oc < 4; ++oc) {
            bf16x8 bo = *(const bf16x8*)(bwb + oc * 1024 + (size_t)rA * 64 + kh * 32 + kg * 8);
            accO[0][oc] = __builtin_amdgcn_mfma_f32_16x16x32_bf16(af[0], bo, accO[0][oc], 0, 0, 0);
            accO[1][oc] = __builtin_amdgcn_mfma_f32_16x16x32_bf16(af[1], bo, accO[1][oc], 0, 0, 0);
        }
    }
    float* ob = out + ((size_t)b << 16);
#pragma unroll
    for (int oc = 0; oc < 4; ++oc) {
        float b2v = bn2b[oc * 16 + rA];
#pragma unroll
        for (int lt = 0; lt < 2; ++lt) {
#pragma unroll
            for (int r = 0; r < 4; ++r)
                ob[(size_t)(oc * 16 + rA) * 1024 + wl0 + lt * 16 + kg * 4 + r] =
                    relu_(accO[lt][oc][r] + b2v);
        }
    }
}

extern "C" void kernel_launch(void* const* d_in, const int* in_sizes, int n_in,
                              void* d_out, int out_size, void* d_ws, size_t ws_size,
                              hipStream_t stream)
{
    const float* x       = (const float*)d_in[0];
    const float* SP      = (const float*)d_in[1];
    const float* trans_w = (const float*)d_in[2];
    const float* bn1_g   = (const float*)d_in[3];
    const float* bn1_b   = (const float*)d_in[4];
    const float* w_nc    = (const float*)d_in[5];
    const float* b_nc    = (const float*)d_in[6];
    const float* w_kc    = (const float*)d_in[7];
    const float* b_kc    = (const float*)d_in[8];
    const float* w_g     = (const float*)d_in[9];
    const float* b_g     = (const float*)d_in[10];
    const float* adj     = (const float*)d_in[11];
    const float* w_sp    = (const float*)d_in[12];
    const float* b_sp    = (const float*)d_in[13];
    const float* back_w  = (const float*)d_in[14];
    const float* bn2_g   = (const float*)d_in[15];
    const float* bn2_b   = (const float*)d_in[16];
    float* out = (float*)d_out;

    float* ws = (float*)d_ws;
    float* P  = ws;                                    // [64][27][1024] fp32
    float* y  = P  + (size_t)B_ * NC_ * L_;            // [64][64][1024] fp32
    float* yn = y  + (size_t)B_ * F_ * L_;             // [64][64][27]
    float* U  = yn + (size_t)B_ * F_ * NC_;            // [64][27][64]
    ushort* Pt   = (ushort*)(U + (size_t)B_ * NC_ * F_); // [64][1024][32] bf16
    ushort* Zwt  = Pt   + (size_t)B_ * L_ * 32;        // [64][64][32] bf16
    ushort* ywb  = Zwt  + (size_t)B_ * F_ * 32;        // [64][64][1024] bf16
    ushort* adjb = ywb  + (size_t)B_ * F_ * L_;        // [1024][1024] bf16
    ushort* bwb  = adjb + (size_t)L_ * L_;             // [64][64] bf16

    k_prep<<<1025, 256, 0, stream>>>(adj, back_w, bn2_g, adjb, bwb);
    k_softmax_pool<<<256, 256, 0, stream>>>(SP, P, Pt);
    k_trans<<<256, 256, 0, stream>>>(x, trans_w, bn1_g, bn1_b, w_sp, y, ywb);
    k_yn_U<<<64, 512, 0, stream>>>(y, P, w_nc, b_nc, yn, U);
    k_sigma_Z<<<64, 256, 0, stream>>>(yn, U, w_kc, b_kc, w_g, Zwt);
    k_fused2<<<512, 256, 0, stream>>>(adjb, ywb, Pt, Zwt, y, b_g, b_sp, bwb, bn2_b, out);
}

// Round 3
// 183.470 us; speedup vs baseline: 2.2289x; 1.5812x over previous
//
#include <hip/hip_runtime.h>

#define B_  64
#define F_  64
#define NC_ 27
#define L_  1024
#define EPSV 1e-5f
#define NCHUNK 16

typedef __bf16 bf16x8 __attribute__((ext_vector_type(8)));
typedef float  f32x4  __attribute__((ext_vector_type(4)));

static __device__ __forceinline__ float relu_(float v) { return fmaxf(v, 0.f); }
static __device__ __forceinline__ ushort f2bf(float f) {
    __bf16 h = (__bf16)f;
    ushort r;
    __builtin_memcpy(&r, &h, 2);
    return r;
}

// ---------------- K0: convert adj -> bf16; back_w*bn2_scale -> bf16 ----------------
__global__ void k_prep(const float* __restrict__ adj, const float* __restrict__ bw,
                       const float* __restrict__ g2, ushort* __restrict__ adjb,
                       ushort* __restrict__ bwb)
{
    int blk = blockIdx.x, t = threadIdx.x;
    if (blk < 1024) {
        int i = (blk * 256 + t) * 4;
        float4 v = *(const float4*)(adj + i);
        ushort4 o;
        o.x = f2bf(v.x); o.y = f2bf(v.y); o.z = f2bf(v.z); o.w = f2bf(v.w);
        *(ushort4*)(adjb + i) = o;
    } else {
        const float rs = 1.f / sqrtf(1.f + EPSV);
        for (int j = t; j < 4096; j += 256) {
            int o = j >> 6;
            bwb[j] = f2bf(bw[j] * g2[o] * rs);
        }
    }
}

// ---------------- K1: softmax over 27 classes + 2x2 maxpool -> P fp32, Pt bf16 ----------------
__global__ void k_softmax_pool(const float* __restrict__ SP, float* __restrict__ P,
                               ushort* __restrict__ Pt)
{
    int tid = blockIdx.x * 256 + threadIdx.x;       // 65536 = B * 1024
    int b = tid >> 10, ol = tid & 1023;
    int oi = ol >> 5, oj = ol & 31;
    float acc[NC_];
#pragma unroll
    for (int c = 0; c < NC_; ++c) acc[c] = 0.f;
    const float* base = SP + (size_t)b * NC_ * 4096;
#pragma unroll
    for (int p = 0; p < 4; ++p) {
        int di = p >> 1, dj = p & 1;
        int off = (2 * oi + di) * 64 + (2 * oj + dj);
        float v[NC_];
        float m = -1e30f;
#pragma unroll
        for (int c = 0; c < NC_; ++c) { v[c] = base[c * 4096 + off]; m = fmaxf(m, v[c]); }
        float s = 0.f;
#pragma unroll
        for (int c = 0; c < NC_; ++c) { v[c] = __expf(v[c] - m); s += v[c]; }
        float inv = 1.f / s;
#pragma unroll
        for (int c = 0; c < NC_; ++c) acc[c] = fmaxf(acc[c], v[c] * inv);
    }
#pragma unroll
    for (int c = 0; c < NC_; ++c)
        P[((size_t)b * NC_ + c) * L_ + ol] = acc[c];
    // transposed bf16 copy, K padded to 32 with zeros: Pt[b][l][c]
    ushort h[32];
#pragma unroll
    for (int c = 0; c < NC_; ++c) h[c] = f2bf(acc[c]);
#pragma unroll
    for (int c = NC_; c < 32; ++c) h[c] = 0;
    ushort* pt = Pt + ((size_t)b * L_ + ol) * 32;
#pragma unroll
    for (int c0 = 0; c0 < 32; c0 += 4)
        *(ushort4*)&pt[c0] = *(ushort4*)&h[c0];
}

// ---------------- K2: 1x1 conv + BN + ReLU -> y fp32 ; yw = y^T @ w_sp^T -> bf16 ----------------
__global__ void k_trans(const float* __restrict__ x, const float* __restrict__ w,
                        const float* __restrict__ g, const float* __restrict__ beta,
                        const float* __restrict__ w_sp,
                        float* __restrict__ y, ushort* __restrict__ ywb)
{
    __shared__ __align__(16) float sW[64 * 68];     // trans_w^T [c][f]
    __shared__ __align__(16) float sS[64 * 68];     // w_sp^T    [f'][f]
    const int t = threadIdx.x;
    const int b = blockIdx.x >> 2;
    const int l = ((blockIdx.x & 3) << 8) + t;
    for (int idx = t; idx < 4096; idx += 256) {
        int f = idx >> 6, c = idx & 63;
        sW[c * 68 + f] = w[idx];
        sS[c * 68 + f] = w_sp[idx];
    }
    __syncthreads();
    float acc[64];
#pragma unroll
    for (int f = 0; f < 64; ++f) acc[f] = 0.f;
    const float* xb = x + ((size_t)b << 16) + l;
    for (int c = 0; c < 64; ++c) {
        float xv = xb[(size_t)c * L_];
#pragma unroll
        for (int f4 = 0; f4 < 16; ++f4) {
            float4 wv = *(const float4*)&sW[c * 68 + f4 * 4];
            acc[f4 * 4 + 0] = fmaf(wv.x, xv, acc[f4 * 4 + 0]);
            acc[f4 * 4 + 1] = fmaf(wv.y, xv, acc[f4 * 4 + 1]);
            acc[f4 * 4 + 2] = fmaf(wv.z, xv, acc[f4 * 4 + 2]);
            acc[f4 * 4 + 3] = fmaf(wv.w, xv, acc[f4 * 4 + 3]);
        }
    }
    const float rs = 1.f / sqrtf(1.f + EPSV);
    float* yb = y + ((size_t)b << 16) + l;
#pragma unroll
    for (int f = 0; f < 64; ++f) {
        acc[f] = relu_(g[f] * rs * acc[f] + beta[f]);
        yb[(size_t)f * L_] = acc[f];
    }
    // yw[f] = sum_f' acc[f'] * w_sp[f][f']
    float yw[64];
#pragma unroll
    for (int f = 0; f < 64; ++f) yw[f] = 0.f;
    for (int fp = 0; fp < 64; ++fp) {
        float v = acc[fp];
#pragma unroll
        for (int f4 = 0; f4 < 16; ++f4) {
            float4 w4 = *(const float4*)&sS[fp * 68 + f4 * 4];
            yw[f4 * 4 + 0] = fmaf(w4.x, v, yw[f4 * 4 + 0]);
            yw[f4 * 4 + 1] = fmaf(w4.y, v, yw[f4 * 4 + 1]);
            yw[f4 * 4 + 2] = fmaf(w4.z, v, yw[f4 * 4 + 2]);
            yw[f4 * 4 + 3] = fmaf(w4.w, v, yw[f4 * 4 + 3]);
        }
    }
    ushort* yp = ywb + ((size_t)b << 16) + l;
#pragma unroll
    for (int f = 0; f < 64; ++f)
        yp[(size_t)f * L_] = f2bf(yw[f]);
}

// ---------------- K3: partial yn/U over one 64-length L-tile per block ----------------
// grid = B * NCHUNK ; partYN/partU[bid][c*64+f], c in [0,27)
__global__ __launch_bounds__(256) void k_yn_U_part(
    const float* __restrict__ y, const float* __restrict__ P,
    const float* __restrict__ w_nc,
    float* __restrict__ partYN, float* __restrict__ partU)
{
    __shared__ __align__(16) float ylds[64 * 68];
    __shared__ __align__(16) float plds[NC_ * 68];
    __shared__ __align__(16) float wlds[NC_ * 68];
    const int t = threadIdx.x;                      // 256
    const int b  = blockIdx.x >> 4;
    const int l0 = (blockIdx.x & 15) << 6;
    const int f = t & 63;
    const int q = t >> 6;                           // 0..3 (wave-uniform)
    const float* yb = y + ((size_t)b << 16);
    const float* Pb = P + (size_t)b * NC_ * L_;
    for (int idx = t; idx < 4096; idx += 256) {
        int ff = idx >> 6, lc = idx & 63;
        ylds[ff * 68 + lc] = yb[(size_t)ff * L_ + l0 + lc];
    }
    for (int idx = t; idx < NC_ * 64; idx += 256) {
        int c = idx >> 6, lc = idx & 63;
        plds[c * 68 + lc] = Pb[(size_t)c * L_ + l0 + lc];
        wlds[c * 68 + lc] = w_nc[(size_t)c * L_ + l0 + lc];
    }
    __syncthreads();
    float pyn[7], pU[7];
#pragma unroll
    for (int r = 0; r < 7; ++r) { pyn[r] = 0.f; pU[r] = 0.f; }
#pragma unroll 4
    for (int l4 = 0; l4 < 16; ++l4) {
        float4 y4 = *(const float4*)&ylds[f * 68 + l4 * 4];
        const float ya[4] = {y4.x, y4.y, y4.z, y4.w};
#pragma unroll
        for (int r = 0; r < 7; ++r) {
            int c = q + (r << 2);
            if (c < NC_) {
#pragma unroll
                for (int i = 0; i < 4; ++i) {
                    int l = l4 * 4 + i;
                    pyn[r] = fmaf(wlds[c * 68 + l], ya[i], pyn[r]);
                    pU[r]  = fmaf(plds[c * 68 + l], ya[i], pU[r]);
                }
            }
        }
    }
    float* oy = partYN + (size_t)blockIdx.x * (NC_ * 64);
    float* ou = partU  + (size_t)blockIdx.x * (NC_ * 64);
#pragma unroll
    for (int r = 0; r < 7; ++r) {
        int c = q + (r << 2);
        if (c < NC_) {
            oy[c * 64 + f] = pyn[r];
            ou[c * 64 + f] = pU[r];
        }
    }
}

// ---------------- K4: reduce partials; sigma = yn·w_kc^T + b_kc ; Z = sigma·U ; Zwt bf16 ----------------
__global__ void k_sigma_Z(const float* __restrict__ partYN, const float* __restrict__ partU,
                          const float* __restrict__ b_nc,
                          const float* __restrict__ w_kc, const float* __restrict__ b_kc,
                          const float* __restrict__ w_g, ushort* __restrict__ Zwt)
{
    __shared__ float syn[F_ * NC_];     // [f][c]
    __shared__ float su[NC_ * F_];      // [k][f]
    __shared__ float swk[NC_ * F_];     // [k][f]
    __shared__ float ssig[NC_ * NC_];   // [c][k]
    __shared__ float sz[NC_ * F_];      // Z [c][f]
    __shared__ float swg[F_ * F_];      // w_g [f][f']
    const int t = threadIdx.x;          // 256
    const int b = blockIdx.x;
    // reduce partials: idx = c*64 + f
    for (int idx = t; idx < NC_ * F_; idx += 256) {
        int c = idx >> 6, f = idx & 63;
        float sy = 0.f, suv = 0.f;
        const float* py = partYN + ((size_t)b * NCHUNK) * (NC_ * 64) + idx;
        const float* pu = partU  + ((size_t)b * NCHUNK) * (NC_ * 64) + idx;
#pragma unroll
        for (int p = 0; p < NCHUNK; ++p) {
            sy  += py[p * (NC_ * 64)];
            suv += pu[p * (NC_ * 64)];
        }
        syn[f * NC_ + c] = sy + b_nc[c];
        su[c * F_ + f]   = suv;
    }
    for (int idx = t; idx < NC_ * F_; idx += 256) swk[idx] = w_kc[idx];
    for (int idx = t; idx < F_ * F_; idx += 256) swg[idx] = w_g[idx];
    __syncthreads();
    for (int idx = t; idx < NC_ * NC_; idx += 256) {
        int c = idx / NC_, k = idx - c * NC_;
        float s = b_kc[k];
        for (int ff = 0; ff < F_; ++ff)
            s = fmaf(syn[ff * NC_ + c], swk[k * F_ + ff], s);
        ssig[c * NC_ + k] = s;
    }
    __syncthreads();
    for (int idx = t; idx < NC_ * F_; idx += 256) {
        int c = idx >> 6, ff = idx & 63;
        float s = 0.f;
        for (int k = 0; k < NC_; ++k)
            s = fmaf(ssig[c * NC_ + k], su[k * F_ + ff], s);
        sz[idx] = s;
    }
    __syncthreads();
    // Zw[c][f] = sum_f' Z[c][f'] * w_g[f][f'] ; store transposed [f][c], c padded to 32
    for (int idx = t; idx < F_ * 32; idx += 256) {
        int f = idx >> 5, c = idx & 31;
        float s = 0.f;
        if (c < NC_)
            for (int fp = 0; fp < F_; ++fp)
                s = fmaf(sz[c * F_ + fp], swg[f * F_ + fp], s);
        Zwt[(size_t)b * F_ * 32 + idx] = f2bf(s);
    }
}

// ---------------- K5: MFMA fused: S=adj·yw^T (K=1024), D=Pt·Zwt^T (K=32), epilogue, back conv ----------------
__global__ __launch_bounds__(256) void k_fused2(
    const ushort* __restrict__ adjb_, const ushort* __restrict__ ywb_,
    const ushort* __restrict__ Pt_, const ushort* __restrict__ Zwt_,
    const float* __restrict__ y, const float* __restrict__ b_g,
    const float* __restrict__ b_sp, const ushort* __restrict__ bwb_,
    const float* __restrict__ bn2b, float* __restrict__ out)
{
    __shared__ float sPre[4 * 32 * 68];
    const int t = threadIdx.x;
    const int w = t >> 6, lane = t & 63;
    const int rA = lane & 15, kg = lane >> 4;
    const int b = blockIdx.x >> 3;
    const int l0 = (blockIdx.x & 7) << 7;           // 128-row tile
    const int wl0 = l0 + w * 32;                    // this wave's 32 rows

    const __bf16* adjb = (const __bf16*)adjb_;
    const __bf16* ywb  = (const __bf16*)ywb_ + ((size_t)b << 16);
    const __bf16* Ptb  = (const __bf16*)Pt_  + ((size_t)b << 15);
    const __bf16* Zwtb = (const __bf16*)Zwt_ + ((size_t)b << 11);
    const __bf16* bwb  = (const __bf16*)bwb_;

    f32x4 accS[2][4], accD[2][4];
#pragma unroll
    for (int i = 0; i < 2; ++i)
#pragma unroll
        for (int j = 0; j < 4; ++j) {
            accS[i][j] = (f32x4){0.f, 0.f, 0.f, 0.f};
            accD[i][j] = (f32x4){0.f, 0.f, 0.f, 0.f};
        }

    // main GEMM: S[l][f] = sum_m adj[l][m] * yw[f][m]
    const __bf16* pa = adjb + (size_t)(wl0 + rA) * 1024 + kg * 8;
    const __bf16* pb = ywb + (size_t)rA * 1024 + kg * 8;
#pragma unroll 4
    for (int ks = 0; ks < 32; ++ks) {
        bf16x8 a0 = *(const bf16x8*)(pa + ks * 32);
        bf16x8 a1 = *(const bf16x8*)(pa + 16 * 1024 + ks * 32);
        bf16x8 f0 = *(const bf16x8*)(pb + 0 * 16384 + ks * 32);
        bf16x8 f1 = *(const bf16x8*)(pb + 1 * 16384 + ks * 32);
        bf16x8 f2 = *(const bf16x8*)(pb + 2 * 16384 + ks * 32);
        bf16x8 f3 = *(const bf16x8*)(pb + 3 * 16384 + ks * 32);
        accS[0][0] = __builtin_amdgcn_mfma_f32_16x16x32_bf16(a0, f0, accS[0][0], 0, 0, 0);
        accS[0][1] = __builtin_amdgcn_mfma_f32_16x16x32_bf16(a0, f1, accS[0][1], 0, 0, 0);
        accS[0][2] = __builtin_amdgcn_mfma_f32_16x16x32_bf16(a0, f2, accS[0][2], 0, 0, 0);
        accS[0][3] = __builtin_amdgcn_mfma_f32_16x16x32_bf16(a0, f3, accS[0][3], 0, 0, 0);
        accS[1][0] = __builtin_amdgcn_mfma_f32_16x16x32_bf16(a1, f0, accS[1][0], 0, 0, 0);
        accS[1][1] = __builtin_amdgcn_mfma_f32_16x16x32_bf16(a1, f1, accS[1][1], 0, 0, 0);
        accS[1][2] = __builtin_amdgcn_mfma_f32_16x16x32_bf16(a1, f2, accS[1][2], 0, 0, 0);
        accS[1][3] = __builtin_amdgcn_mfma_f32_16x16x32_bf16(a1, f3, accS[1][3], 0, 0, 0);
    }

    // dynamic path: D[l][f] = sum_c Pt[l][c] * Zwt[f][c], K=32 (c padded)
    {
        const __bf16* qa = Ptb + (size_t)(wl0 + rA) * 32 + kg * 8;
        bf16x8 a0 = *(const bf16x8*)(qa);
        bf16x8 a1 = *(const bf16x8*)(qa + 16 * 32);
        const __bf16* qb = Zwtb + (size_t)rA * 32 + kg * 8;
        bf16x8 z0 = *(const bf16x8*)(qb + 0 * 512);
        bf16x8 z1 = *(const bf16x8*)(qb + 1 * 512);
        bf16x8 z2 = *(const bf16x8*)(qb + 2 * 512);
        bf16x8 z3 = *(const bf16x8*)(qb + 3 * 512);
        accD[0][0] = __builtin_amdgcn_mfma_f32_16x16x32_bf16(a0, z0, accD[0][0], 0, 0, 0);
        accD[0][1] = __builtin_amdgcn_mfma_f32_16x16x32_bf16(a0, z1, accD[0][1], 0, 0, 0);
        accD[0][2] = __builtin_amdgcn_mfma_f32_16x16x32_bf16(a0, z2, accD[0][2], 0, 0, 0);
        accD[0][3] = __builtin_amdgcn_mfma_f32_16x16x32_bf16(a0, z3, accD[0][3], 0, 0, 0);
        accD[1][0] = __builtin_amdgcn_mfma_f32_16x16x32_bf16(a1, z0, accD[1][0], 0, 0, 0);
        accD[1][1] = __builtin_amdgcn_mfma_f32_16x16x32_bf16(a1, z1, accD[1][1], 0, 0, 0);
        accD[1][2] = __builtin_amdgcn_mfma_f32_16x16x32_bf16(a1, z2, accD[1][2], 0, 0, 0);
        accD[1][3] = __builtin_amdgcn_mfma_f32_16x16x32_bf16(a1, z3, accD[1][3], 0, 0, 0);
    }

    // epilogue: pre = relu(D + b_g) + relu(S + b_sp) + 3*y  -> LDS (fp32, pad 68)
    float bg4[4], bs4[4];
#pragma unroll
    for (int fc = 0; fc < 4; ++fc) { bg4[fc] = b_g[fc * 16 + rA]; bs4[fc] = b_sp[fc * 16 + rA]; }
    const float* yb = y + ((size_t)b << 16);
    const int wOff = w * 32 * 68;
#pragma unroll
    for (int lt = 0; lt < 2; ++lt) {
        int lbase = wl0 + lt * 16 + kg * 4;
        int row = lt * 16 + kg * 4;
#pragma unroll
        for (int fc = 0; fc < 4; ++fc) {
            int f = fc * 16 + rA;
            float4 yv = *(const float4*)(yb + (size_t)f * 1024 + lbase);
            f32x4 s = accS[lt][fc], d = accD[lt][fc];
            sPre[wOff + (row + 0) * 68 + f] = relu_(d[0] + bg4[fc]) + relu_(s[0] + bs4[fc]) + 3.f * yv.x;
            sPre[wOff + (row + 1) * 68 + f] = relu_(d[1] + bg4[fc]) + relu_(s[1] + bs4[fc]) + 3.f * yv.y;
            sPre[wOff + (row + 2) * 68 + f] = relu_(d[2] + bg4[fc]) + relu_(s[2] + bs4[fc]) + 3.f * yv.z;
            sPre[wOff + (row + 3) * 68 + f] = relu_(d[3] + bg4[fc]) + relu_(s[3] + bs4[fc]) + 3.f * yv.w;
        }
    }
    __syncthreads();

    // back conv: out[o][l] = relu( sum_f pre[l][f] * bwb[o][f] + bn2b[o] )
    f32x4 accO[2][4];
#pragma unroll
    for (int i = 0; i < 2; ++i)
#pragma unroll
        for (int j = 0; j < 4; ++j) accO[i][j] = (f32x4){0.f, 0.f, 0.f, 0.f};
#pragma unroll
    for (int kh = 0; kh < 2; ++kh) {
        bf16x8 af[2];
#pragma unroll
        for (int lt = 0; lt < 2; ++lt) {
            int off = wOff + (lt * 16 + rA) * 68 + kh * 32 + kg * 8;
            float4 u0 = *(const float4*)&sPre[off];
            float4 u1 = *(const float4*)&sPre[off + 4];
            bf16x8 a;
            a[0] = (__bf16)u0.x; a[1] = (__bf16)u0.y; a[2] = (__bf16)u0.z; a[3] = (__bf16)u0.w;
            a[4] = (__bf16)u1.x; a[5] = (__bf16)u1.y; a[6] = (__bf16)u1.z; a[7] = (__bf16)u1.w;
            af[lt] = a;
        }
#pragma unroll
        for (int oc = 0; oc < 4; ++oc) {
            bf16x8 bo = *(const bf16x8*)(bwb + oc * 1024 + (size_t)rA * 64 + kh * 32 + kg * 8);
            accO[0][oc] = __builtin_amdgcn_mfma_f32_16x16x32_bf16(af[0], bo, accO[0][oc], 0, 0, 0);
            accO[1][oc] = __builtin_amdgcn_mfma_f32_16x16x32_bf16(af[1], bo, accO[1][oc], 0, 0, 0);
        }
    }
    float* ob = out + ((size_t)b << 16);
#pragma unroll
    for (int oc = 0; oc < 4; ++oc) {
        float b2v = bn2b[oc * 16 + rA];
#pragma unroll
        for (int lt = 0; lt < 2; ++lt) {
#pragma unroll
            for (int r = 0; r < 4; ++r)
                ob[(size_t)(oc * 16 + rA) * 1024 + wl0 + lt * 16 + kg * 4 + r] =
                    relu_(accO[lt][oc][r] + b2v);
        }
    }
}

extern "C" void kernel_launch(void* const* d_in, const int* in_sizes, int n_in,
                              void* d_out, int out_size, void* d_ws, size_t ws_size,
                              hipStream_t stream)
{
    const float* x       = (const float*)d_in[0];
    const float* SP      = (const float*)d_in[1];
    const float* trans_w = (const float*)d_in[2];
    const float* bn1_g   = (const float*)d_in[3];
    const float* bn1_b   = (const float*)d_in[4];
    const float* w_nc    = (const float*)d_in[5];
    const float* b_nc    = (const float*)d_in[6];
    const float* w_kc    = (const float*)d_in[7];
    const float* b_kc    = (const float*)d_in[8];
    const float* w_g     = (const float*)d_in[9];
    const float* b_g     = (const float*)d_in[10];
    const float* adj     = (const float*)d_in[11];
    const float* w_sp    = (const float*)d_in[12];
    const float* b_sp    = (const float*)d_in[13];
    const float* back_w  = (const float*)d_in[14];
    const float* bn2_g   = (const float*)d_in[15];
    const float* bn2_b   = (const float*)d_in[16];
    float* out = (float*)d_out;

    float* ws = (float*)d_ws;
    float* P      = ws;                                     // [64][27][1024] fp32
    float* y      = P + (size_t)B_ * NC_ * L_;              // [64][64][1024] fp32
    float* partYN = y + (size_t)B_ * F_ * L_;               // [B*16][27*64] fp32
    float* partU  = partYN + (size_t)B_ * NCHUNK * NC_ * F_;// [B*16][27*64] fp32
    ushort* Pt   = (ushort*)(partU + (size_t)B_ * NCHUNK * NC_ * F_); // [64][1024][32] bf16
    ushort* Zwt  = Pt   + (size_t)B_ * L_ * 32;             // [64][64][32] bf16
    ushort* ywb  = Zwt  + (size_t)B_ * F_ * 32;             // [64][64][1024] bf16
    ushort* adjb = ywb  + (size_t)B_ * F_ * L_;             // [1024][1024] bf16
    ushort* bwb  = adjb + (size_t)L_ * L_;                  // [64][64] bf16

    k_prep<<<1025, 256, 0, stream>>>(adj, back_w, bn2_g, adjb, bwb);
    k_softmax_pool<<<256, 256, 0, stream>>>(SP, P, Pt);
    k_trans<<<256, 256, 0, stream>>>(x, trans_w, bn1_g, bn1_b, w_sp, y, ywb);
    k_yn_U_part<<<B_ * NCHUNK, 256, 0, stream>>>(y, P, w_nc, partYN, partU);
    k_sigma_Z<<<64, 256, 0, stream>>>(partYN, partU, b_nc, w_kc, b_kc, w_g, Zwt);
    k_fused2<<<512, 256, 0, stream>>>(adjb, ywb, Pt, Zwt, y, b_g, b_sp, bwb, bn2_b, out);
}

// Round 4
// 134.427 us; speedup vs baseline: 3.0420x; 1.3648x over previous
//
#include <hip/hip_runtime.h>

#define B_  64
#define F_  64
#define NC_ 27
#define L_  1024
#define EPSV 1e-5f
#define NCHUNK 16

typedef __bf16 bf16x8 __attribute__((ext_vector_type(8)));
typedef float  f32x4  __attribute__((ext_vector_type(4)));

static __device__ __forceinline__ float relu_(float v) { return fmaxf(v, 0.f); }
static __device__ __forceinline__ ushort f2bf(float f) {
    __bf16 h = (__bf16)f;
    ushort r;
    __builtin_memcpy(&r, &h, 2);
    return r;
}
static __device__ __forceinline__ bf16x8 cvt8(float4 a, float4 b) {
    bf16x8 r;
    r[0] = (__bf16)a.x; r[1] = (__bf16)a.y; r[2] = (__bf16)a.z; r[3] = (__bf16)a.w;
    r[4] = (__bf16)b.x; r[5] = (__bf16)b.y; r[6] = (__bf16)b.z; r[7] = (__bf16)b.w;
    return r;
}

// ---------------- K0: convert adj -> bf16; back_w*bn2_scale -> bf16 ----------------
__global__ void k_prep(const float* __restrict__ adj, const float* __restrict__ bw,
                       const float* __restrict__ g2, ushort* __restrict__ adjb,
                       ushort* __restrict__ bwb)
{
    int blk = blockIdx.x, t = threadIdx.x;
    if (blk < 1024) {
        int i = (blk * 256 + t) * 4;
        float4 v = *(const float4*)(adj + i);
        ushort4 o;
        o.x = f2bf(v.x); o.y = f2bf(v.y); o.z = f2bf(v.z); o.w = f2bf(v.w);
        *(ushort4*)(adjb + i) = o;
    } else {
        const float rs = 1.f / sqrtf(1.f + EPSV);
        for (int j = t; j < 4096; j += 256) {
            int o = j >> 6;
            bwb[j] = f2bf(bw[j] * g2[o] * rs);
        }
    }
}

// ---------------- K1: softmax over 27 classes + 2x2 maxpool -> P fp32, Pt bf16 ----------------
__global__ void k_softmax_pool(const float* __restrict__ SP, float* __restrict__ P,
                               ushort* __restrict__ Pt)
{
    int tid = blockIdx.x * 256 + threadIdx.x;       // 65536 = B * 1024
    int b = tid >> 10, ol = tid & 1023;
    int oi = ol >> 5, oj = ol & 31;
    float acc[NC_];
#pragma unroll
    for (int c = 0; c < NC_; ++c) acc[c] = 0.f;
    const float* base = SP + (size_t)b * NC_ * 4096;
#pragma unroll
    for (int p = 0; p < 4; ++p) {
        int di = p >> 1, dj = p & 1;
        int off = (2 * oi + di) * 64 + (2 * oj + dj);
        float v[NC_];
        float m = -1e30f;
#pragma unroll
        for (int c = 0; c < NC_; ++c) { v[c] = base[c * 4096 + off]; m = fmaxf(m, v[c]); }
        float s = 0.f;
#pragma unroll
        for (int c = 0; c < NC_; ++c) { v[c] = __expf(v[c] - m); s += v[c]; }
        float inv = 1.f / s;
#pragma unroll
        for (int c = 0; c < NC_; ++c) acc[c] = fmaxf(acc[c], v[c] * inv);
    }
#pragma unroll
    for (int c = 0; c < NC_; ++c)
        P[((size_t)b * NC_ + c) * L_ + ol] = acc[c];
    // transposed bf16 copy, K padded to 32 with zeros: Pt[b][l][c]
    ushort h[32];
#pragma unroll
    for (int c = 0; c < NC_; ++c) h[c] = f2bf(acc[c]);
#pragma unroll
    for (int c = NC_; c < 32; ++c) h[c] = 0;
    ushort* pt = Pt + ((size_t)b * L_ + ol) * 32;
#pragma unroll
    for (int c0 = 0; c0 < 32; c0 += 4)
        *(ushort4*)&pt[c0] = *(ushort4*)&h[c0];
}

// ---------------- K2: MFMA trans: t = relu(BN(x·w^T)) -> y fp32 ; yw = t·w_sp^T -> bf16 ----------------
__global__ __launch_bounds__(256) void k_trans_mfma(
    const float* __restrict__ x, const float* __restrict__ w,
    const float* __restrict__ g, const float* __restrict__ beta,
    const float* __restrict__ w_sp,
    float* __restrict__ y, ushort* __restrict__ ywb)
{
    __shared__ __align__(16) ushort sT[4][32][72];   // per-wave t tile bf16 [l][f]
    const int t = threadIdx.x;
    const int wv = t >> 6, lane = t & 63;
    const int rA = lane & 15, kg = lane >> 4;
    const int b = blockIdx.x >> 3;
    const int l0 = (blockIdx.x & 7) << 7;
    const int wl0 = l0 + wv * 32;

    const float* xb = x + ((size_t)b << 16);

    // MFMA1: t[l][f] = sum_c x[c][l] * w[f][c]
    f32x4 acc[2][4];
#pragma unroll
    for (int i = 0; i < 2; ++i)
#pragma unroll
        for (int j = 0; j < 4; ++j) acc[i][j] = (f32x4){0.f, 0.f, 0.f, 0.f};
#pragma unroll
    for (int ks = 0; ks < 2; ++ks) {
        bf16x8 a[2];
#pragma unroll
        for (int lt = 0; lt < 2; ++lt) {
            const int l = wl0 + lt * 16 + rA;
            bf16x8 av;
#pragma unroll
            for (int j = 0; j < 8; ++j)
                av[j] = (__bf16)xb[(size_t)(ks * 32 + kg * 8 + j) * 1024 + l];
            a[lt] = av;
        }
#pragma unroll
        for (int fc = 0; fc < 4; ++fc) {
            const float* wp = w + (fc * 16 + rA) * 64 + ks * 32 + kg * 8;
            bf16x8 bv = cvt8(*(const float4*)wp, *(const float4*)(wp + 4));
            acc[0][fc] = __builtin_amdgcn_mfma_f32_16x16x32_bf16(a[0], bv, acc[0][fc], 0, 0, 0);
            acc[1][fc] = __builtin_amdgcn_mfma_f32_16x16x32_bf16(a[1], bv, acc[1][fc], 0, 0, 0);
        }
    }

    // epilogue: BN + ReLU ; y fp32 -> global ; t bf16 -> LDS
    const float rs = 1.f / sqrtf(1.f + EPSV);
    float* yg = y + ((size_t)b << 16);
#pragma unroll
    for (int fc = 0; fc < 4; ++fc) {
        const int f = fc * 16 + rA;
        const float sc = g[f] * rs, bb = beta[f];
#pragma unroll
        for (int lt = 0; lt < 2; ++lt) {
            float4 tv;
            float* tp = (float*)&tv;
#pragma unroll
            for (int r = 0; r < 4; ++r) {
                float v = relu_(sc * acc[lt][fc][r] + bb);
                tp[r] = v;
                sT[wv][lt * 16 + kg * 4 + r][f] = f2bf(v);
            }
            *(float4*)(yg + (size_t)f * 1024 + wl0 + lt * 16 + kg * 4) = tv;
        }
    }
    __syncthreads();

    // MFMA2: yw[l][f] = sum_f' t[l][f'] * w_sp[f][f']
    f32x4 acc2[2][4];
#pragma unroll
    for (int i = 0; i < 2; ++i)
#pragma unroll
        for (int j = 0; j < 4; ++j) acc2[i][j] = (f32x4){0.f, 0.f, 0.f, 0.f};
#pragma unroll
    for (int kh = 0; kh < 2; ++kh) {
        bf16x8 a[2];
#pragma unroll
        for (int lt = 0; lt < 2; ++lt)
            a[lt] = *(const bf16x8*)&sT[wv][lt * 16 + rA][kh * 32 + kg * 8];
#pragma unroll
        for (int fc = 0; fc < 4; ++fc) {
            const float* wp = w_sp + (fc * 16 + rA) * 64 + kh * 32 + kg * 8;
            bf16x8 bv = cvt8(*(const float4*)wp, *(const float4*)(wp + 4));
            acc2[0][fc] = __builtin_amdgcn_mfma_f32_16x16x32_bf16(a[0], bv, acc2[0][fc], 0, 0, 0);
            acc2[1][fc] = __builtin_amdgcn_mfma_f32_16x16x32_bf16(a[1], bv, acc2[1][fc], 0, 0, 0);
        }
    }
    ushort* yp = ywb + ((size_t)b << 16);
#pragma unroll
    for (int fc = 0; fc < 4; ++fc) {
        const int f = fc * 16 + rA;
#pragma unroll
        for (int lt = 0; lt < 2; ++lt) {
            ushort4 ov;
            ov.x = f2bf(acc2[lt][fc][0]);
            ov.y = f2bf(acc2[lt][fc][1]);
            ov.z = f2bf(acc2[lt][fc][2]);
            ov.w = f2bf(acc2[lt][fc][3]);
            *(ushort4*)(yp + (size_t)f * 1024 + wl0 + lt * 16 + kg * 4) = ov;
        }
    }
}

// ---------------- K3: partial yn/U over one 64-length L-tile per block ----------------
// grid = B * NCHUNK ; partYN/partU[bid][c*64+f], c in [0,27)
__global__ __launch_bounds__(256) void k_yn_U_part(
    const float* __restrict__ y, const float* __restrict__ P,
    const float* __restrict__ w_nc,
    float* __restrict__ partYN, float* __restrict__ partU)
{
    __shared__ __align__(16) float ylds[64 * 68];
    __shared__ __align__(16) float plds[NC_ * 68];
    __shared__ __align__(16) float wlds[NC_ * 68];
    const int t = threadIdx.x;                      // 256
    const int b  = blockIdx.x >> 4;
    const int l0 = (blockIdx.x & 15) << 6;
    const int f = t & 63;
    const int q = t >> 6;                           // 0..3 (wave-uniform)
    const float* yb = y + ((size_t)b << 16);
    const float* Pb = P + (size_t)b * NC_ * L_;
    for (int idx = t; idx < 4096; idx += 256) {
        int ff = idx >> 6, lc = idx & 63;
        ylds[ff * 68 + lc] = yb[(size_t)ff * L_ + l0 + lc];
    }
    for (int idx = t; idx < NC_ * 64; idx += 256) {
        int c = idx >> 6, lc = idx & 63;
        plds[c * 68 + lc] = Pb[(size_t)c * L_ + l0 + lc];
        wlds[c * 68 + lc] = w_nc[(size_t)c * L_ + l0 + lc];
    }
    __syncthreads();
    float pyn[7], pU[7];
#pragma unroll
    for (int r = 0; r < 7; ++r) { pyn[r] = 0.f; pU[r] = 0.f; }
#pragma unroll 4
    for (int l4 = 0; l4 < 16; ++l4) {
        float4 y4 = *(const float4*)&ylds[f * 68 + l4 * 4];
        const float ya[4] = {y4.x, y4.y, y4.z, y4.w};
#pragma unroll
        for (int r = 0; r < 7; ++r) {
            int c = q + (r << 2);
            if (c < NC_) {
#pragma unroll
                for (int i = 0; i < 4; ++i) {
                    int l = l4 * 4 + i;
                    pyn[r] = fmaf(wlds[c * 68 + l], ya[i], pyn[r]);
                    pU[r]  = fmaf(plds[c * 68 + l], ya[i], pU[r]);
                }
            }
        }
    }
    float* oy = partYN + (size_t)blockIdx.x * (NC_ * 64);
    float* ou = partU  + (size_t)blockIdx.x * (NC_ * 64);
#pragma unroll
    for (int r = 0; r < 7; ++r) {
        int c = q + (r << 2);
        if (c < NC_) {
            oy[c * 64 + f] = pyn[r];
            ou[c * 64 + f] = pU[r];
        }
    }
}

// ---------------- K4: reduce partials; sigma = yn·w_kc^T + b_kc ; Z = sigma·U ; Zwt bf16 ----------------
__global__ void k_sigma_Z(const float* __restrict__ partYN, const float* __restrict__ partU,
                          const float* __restrict__ b_nc,
                          const float* __restrict__ w_kc, const float* __restrict__ b_kc,
                          const float* __restrict__ w_g, ushort* __restrict__ Zwt)
{
    __shared__ float syn[F_ * NC_];     // [f][c]
    __shared__ float su[NC_ * F_];      // [k][f]
    __shared__ float swk[NC_ * F_];     // [k][f]
    __shared__ float ssig[NC_ * NC_];   // [c][k]
    __shared__ float sz[NC_ * F_];      // Z [c][f]
    __shared__ float swg[F_ * F_];      // w_g [f][f']
    const int t = threadIdx.x;          // 256
    const int b = blockIdx.x;
    // reduce partials: idx = c*64 + f
    for (int idx = t; idx < NC_ * F_; idx += 256) {
        int c = idx >> 6, f = idx & 63;
        float sy = 0.f, suv = 0.f;
        const float* py = partYN + ((size_t)b * NCHUNK) * (NC_ * 64) + idx;
        const float* pu = partU  + ((size_t)b * NCHUNK) * (NC_ * 64) + idx;
#pragma unroll
        for (int p = 0; p < NCHUNK; ++p) {
            sy  += py[p * (NC_ * 64)];
            suv += pu[p * (NC_ * 64)];
        }
        syn[f * NC_ + c] = sy + b_nc[c];
        su[c * F_ + f]   = suv;
    }
    for (int idx = t; idx < NC_ * F_; idx += 256) swk[idx] = w_kc[idx];
    for (int idx = t; idx < F_ * F_; idx += 256) swg[idx] = w_g[idx];
    __syncthreads();
    for (int idx = t; idx < NC_ * NC_; idx += 256) {
        int c = idx / NC_, k = idx - c * NC_;
        float s = b_kc[k];
        for (int ff = 0; ff < F_; ++ff)
            s = fmaf(syn[ff * NC_ + c], swk[k * F_ + ff], s);
        ssig[c * NC_ + k] = s;
    }
    __syncthreads();
    for (int idx = t; idx < NC_ * F_; idx += 256) {
        int c = idx >> 6, ff = idx & 63;
        float s = 0.f;
        for (int k = 0; k < NC_; ++k)
            s = fmaf(ssig[c * NC_ + k], su[k * F_ + ff], s);
        sz[idx] = s;
    }
    __syncthreads();
    // Zw[c][f] = sum_f' Z[c][f'] * w_g[f][f'] ; store transposed [f][c], c padded to 32
    for (int idx = t; idx < F_ * 32; idx += 256) {
        int f = idx >> 5, c = idx & 31;
        float s = 0.f;
        if (c < NC_)
            for (int fp = 0; fp < F_; ++fp)
                s = fmaf(sz[c * F_ + fp], swg[f * F_ + fp], s);
        Zwt[(size_t)b * F_ * 32 + idx] = f2bf(s);
    }
}

// ---------------- K5: MFMA fused: S=adj·yw^T (K=1024), D=Pt·Zwt^T (K=32), epilogue, back conv ----------------
__global__ __launch_bounds__(256) void k_fused2(
    const ushort* __restrict__ adjb_, const ushort* __restrict__ ywb_,
    const ushort* __restrict__ Pt_, const ushort* __restrict__ Zwt_,
    const float* __restrict__ y, const float* __restrict__ b_g,
    const float* __restrict__ b_sp, const ushort* __restrict__ bwb_,
    const float* __restrict__ bn2b, float* __restrict__ out)
{
    __shared__ float sPre[4 * 32 * 68];
    const int t = threadIdx.x;
    const int w = t >> 6, lane = t & 63;
    const int rA = lane & 15, kg = lane >> 4;
    const int b = blockIdx.x >> 3;
    const int l0 = (blockIdx.x & 7) << 7;           // 128-row tile
    const int wl0 = l0 + w * 32;                    // this wave's 32 rows

    const __bf16* adjb = (const __bf16*)adjb_;
    const __bf16* ywb  = (const __bf16*)ywb_ + ((size_t)b << 16);
    const __bf16* Ptb  = (const __bf16*)Pt_  + ((size_t)b << 15);
    const __bf16* Zwtb = (const __bf16*)Zwt_ + ((size_t)b << 11);
    const __bf16* bwb  = (const __bf16*)bwb_;

    f32x4 accS[2][4], accD[2][4];
#pragma unroll
    for (int i = 0; i < 2; ++i)
#pragma unroll
        for (int j = 0; j < 4; ++j) {
            accS[i][j] = (f32x4){0.f, 0.f, 0.f, 0.f};
            accD[i][j] = (f32x4){0.f, 0.f, 0.f, 0.f};
        }

    // main GEMM: S[l][f] = sum_m adj[l][m] * yw[f][m]
    const __bf16* pa = adjb + (size_t)(wl0 + rA) * 1024 + kg * 8;
    const __bf16* pb = ywb + (size_t)rA * 1024 + kg * 8;
#pragma unroll 4
    for (int ks = 0; ks < 32; ++ks) {
        bf16x8 a0 = *(const bf16x8*)(pa + ks * 32);
        bf16x8 a1 = *(const bf16x8*)(pa + 16 * 1024 + ks * 32);
        bf16x8 f0 = *(const bf16x8*)(pb + 0 * 16384 + ks * 32);
        bf16x8 f1 = *(const bf16x8*)(pb + 1 * 16384 + ks * 32);
        bf16x8 f2 = *(const bf16x8*)(pb + 2 * 16384 + ks * 32);
        bf16x8 f3 = *(const bf16x8*)(pb + 3 * 16384 + ks * 32);
        accS[0][0] = __builtin_amdgcn_mfma_f32_16x16x32_bf16(a0, f0, accS[0][0], 0, 0, 0);
        accS[0][1] = __builtin_amdgcn_mfma_f32_16x16x32_bf16(a0, f1, accS[0][1], 0, 0, 0);
        accS[0][2] = __builtin_amdgcn_mfma_f32_16x16x32_bf16(a0, f2, accS[0][2], 0, 0, 0);
        accS[0][3] = __builtin_amdgcn_mfma_f32_16x16x32_bf16(a0, f3, accS[0][3], 0, 0, 0);
        accS[1][0] = __builtin_amdgcn_mfma_f32_16x16x32_bf16(a1, f0, accS[1][0], 0, 0, 0);
        accS[1][1] = __builtin_amdgcn_mfma_f32_16x16x32_bf16(a1, f1, accS[1][1], 0, 0, 0);
        accS[1][2] = __builtin_amdgcn_mfma_f32_16x16x32_bf16(a1, f2, accS[1][2], 0, 0, 0);
        accS[1][3] = __builtin_amdgcn_mfma_f32_16x16x32_bf16(a1, f3, accS[1][3], 0, 0, 0);
    }

    // dynamic path: D[l][f] = sum_c Pt[l][c] * Zwt[f][c], K=32 (c padded)
    {
        const __bf16* qa = Ptb + (size_t)(wl0 + rA) * 32 + kg * 8;
        bf16x8 a0 = *(const bf16x8*)(qa);
        bf16x8 a1 = *(const bf16x8*)(qa + 16 * 32);
        const __bf16* qb = Zwtb + (size_t)rA * 32 + kg * 8;
        bf16x8 z0 = *(const bf16x8*)(qb + 0 * 512);
        bf16x8 z1 = *(const bf16x8*)(qb + 1 * 512);
        bf16x8 z2 = *(const bf16x8*)(qb + 2 * 512);
        bf16x8 z3 = *(const bf16x8*)(qb + 3 * 512);
        accD[0][0] = __builtin_amdgcn_mfma_f32_16x16x32_bf16(a0, z0, accD[0][0], 0, 0, 0);
        accD[0][1] = __builtin_amdgcn_mfma_f32_16x16x32_bf16(a0, z1, accD[0][1], 0, 0, 0);
        accD[0][2] = __builtin_amdgcn_mfma_f32_16x16x32_bf16(a0, z2, accD[0][2], 0, 0, 0);
        accD[0][3] = __builtin_amdgcn_mfma_f32_16x16x32_bf16(a0, z3, accD[0][3], 0, 0, 0);
        accD[1][0] = __builtin_amdgcn_mfma_f32_16x16x32_bf16(a1, z0, accD[1][0], 0, 0, 0);
        accD[1][1] = __builtin_amdgcn_mfma_f32_16x16x32_bf16(a1, z1, accD[1][1], 0, 0, 0);
        accD[1][2] = __builtin_amdgcn_mfma_f32_16x16x32_bf16(a1, z2, accD[1][2], 0, 0, 0);
        accD[1][3] = __builtin_amdgcn_mfma_f32_16x16x32_bf16(a1, z3, accD[1][3], 0, 0, 0);
    }

    // epilogue: pre = relu(D + b_g) + relu(S + b_sp) + 3*y  -> LDS (fp32, pad 68)
    float bg4[4], bs4[4];
#pragma unroll
    for (int fc = 0; fc < 4; ++fc) { bg4[fc] = b_g[fc * 16 + rA]; bs4[fc] = b_sp[fc * 16 + rA]; }
    const float* yb = y + ((size_t)b << 16);
    const int wOff = w * 32 * 68;
#pragma unroll
    for (int lt = 0; lt < 2; ++lt) {
        int lbase = wl0 + lt * 16 + kg * 4;
        int row = lt * 16 + kg * 4;
#pragma unroll
        for (int fc = 0; fc < 4; ++fc) {
            int f = fc * 16 + rA;
            float4 yv = *(const float4*)(yb + (size_t)f * 1024 + lbase);
            f32x4 s = accS[lt][fc], d = accD[lt][fc];
            sPre[wOff + (row + 0) * 68 + f] = relu_(d[0] + bg4[fc]) + relu_(s[0] + bs4[fc]) + 3.f * yv.x;
            sPre[wOff + (row + 1) * 68 + f] = relu_(d[1] + bg4[fc]) + relu_(s[1] + bs4[fc]) + 3.f * yv.y;
            sPre[wOff + (row + 2) * 68 + f] = relu_(d[2] + bg4[fc]) + relu_(s[2] + bs4[fc]) + 3.f * yv.z;
            sPre[wOff + (row + 3) * 68 + f] = relu_(d[3] + bg4[fc]) + relu_(s[3] + bs4[fc]) + 3.f * yv.w;
        }
    }
    __syncthreads();

    // back conv: out[o][l] = relu( sum_f pre[l][f] * bwb[o][f] + bn2b[o] )
    f32x4 accO[2][4];
#pragma unroll
    for (int i = 0; i < 2; ++i)
#pragma unroll
        for (int j = 0; j < 4; ++j) accO[i][j] = (f32x4){0.f, 0.f, 0.f, 0.f};
#pragma unroll
    for (int kh = 0; kh < 2; ++kh) {
        bf16x8 af[2];
#pragma unroll
        for (int lt = 0; lt < 2; ++lt) {
            int off = wOff + (lt * 16 + rA) * 68 + kh * 32 + kg * 8;
            float4 u0 = *(const float4*)&sPre[off];
            float4 u1 = *(const float4*)&sPre[off + 4];
            bf16x8 a;
            a[0] = (__bf16)u0.x; a[1] = (__bf16)u0.y; a[2] = (__bf16)u0.z; a[3] = (__bf16)u0.w;
            a[4] = (__bf16)u1.x; a[5] = (__bf16)u1.y; a[6] = (__bf16)u1.z; a[7] = (__bf16)u1.w;
            af[lt] = a;
        }
#pragma unroll
        for (int oc = 0; oc < 4; ++oc) {
            bf16x8 bo = *(const bf16x8*)(bwb + oc * 1024 + (size_t)rA * 64 + kh * 32 + kg * 8);
            accO[0][oc] = __builtin_amdgcn_mfma_f32_16x16x32_bf16(af[0], bo, accO[0][oc], 0, 0, 0);
            accO[1][oc] = __builtin_amdgcn_mfma_f32_16x16x32_bf16(af[1], bo, accO[1][oc], 0, 0, 0);
        }
    }
    float* ob = out + ((size_t)b << 16);
#pragma unroll
    for (int oc = 0; oc < 4; ++oc) {
        float b2v = bn2b[oc * 16 + rA];
#pragma unroll
        for (int lt = 0; lt < 2; ++lt) {
#pragma unroll
            for (int r = 0; r < 4; ++r)
                ob[(size_t)(oc * 16 + rA) * 1024 + wl0 + lt * 16 + kg * 4 + r] =
                    relu_(accO[lt][oc][r] + b2v);
        }
    }
}

extern "C" void kernel_launch(void* const* d_in, const int* in_sizes, int n_in,
                              void* d_out, int out_size, void* d_ws, size_t ws_size,
                              hipStream_t stream)
{
    const float* x       = (const float*)d_in[0];
    const float* SP      = (const float*)d_in[1];
    const float* trans_w = (const float*)d_in[2];
    const float* bn1_g   = (const float*)d_in[3];
    const float* bn1_b   = (const float*)d_in[4];
    const float* w_nc    = (const float*)d_in[5];
    const float* b_nc    = (const float*)d_in[6];
    const float* w_kc    = (const float*)d_in[7];
    const float* b_kc    = (const float*)d_in[8];
    const float* w_g     = (const float*)d_in[9];
    const float* b_g     = (const float*)d_in[10];
    const float* adj     = (const float*)d_in[11];
    const float* w_sp    = (const float*)d_in[12];
    const float* b_sp    = (const float*)d_in[13];
    const float* back_w  = (const float*)d_in[14];
    const float* bn2_g   = (const float*)d_in[15];
    const float* bn2_b   = (const float*)d_in[16];
    float* out = (float*)d_out;

    float* ws = (float*)d_ws;
    float* P      = ws;                                     // [64][27][1024] fp32
    float* y      = P + (size_t)B_ * NC_ * L_;              // [64][64][1024] fp32
    float* partYN = y + (size_t)B_ * F_ * L_;               // [B*16][27*64] fp32
    float* partU  = partYN + (size_t)B_ * NCHUNK * NC_ * F_;// [B*16][27*64] fp32
    ushort* Pt   = (ushort*)(partU + (size_t)B_ * NCHUNK * NC_ * F_); // [64][1024][32] bf16
    ushort* Zwt  = Pt   + (size_t)B_ * L_ * 32;             // [64][64][32] bf16
    ushort* ywb  = Zwt  + (size_t)B_ * F_ * 32;             // [64][64][1024] bf16
    ushort* adjb = ywb  + (size_t)B_ * F_ * L_;             // [1024][1024] bf16
    ushort* bwb  = adjb + (size_t)L_ * L_;                  // [64][64] bf16

    k_prep<<<1025, 256, 0, stream>>>(adj, back_w, bn2_g, adjb, bwb);
    k_softmax_pool<<<256, 256, 0, stream>>>(SP, P, Pt);
    k_trans_mfma<<<512, 256, 0, stream>>>(x, trans_w, bn1_g, bn1_b, w_sp, y, ywb);
    k_yn_U_part<<<B_ * NCHUNK, 256, 0, stream>>>(y, P, w_nc, partYN, partU);
    k_sigma_Z<<<64, 256, 0, stream>>>(partYN, partU, b_nc, w_kc, b_kc, w_g, Zwt);
    k_fused2<<<512, 256, 0, stream>>>(adjb, ywb, Pt, Zwt, y, b_g, b_sp, bwb, bn2_b, out);
}

// Round 5
// 113.700 us; speedup vs baseline: 3.5966x; 1.1823x over previous
//
#include <hip/hip_runtime.h>

#define B_  64
#define F_  64
#define NC_ 27
#define L_  1024
#define EPSV 1e-5f
#define NCHUNK 16

typedef __bf16 bf16x8 __attribute__((ext_vector_type(8)));
typedef float  f32x4  __attribute__((ext_vector_type(4)));

static __device__ __forceinline__ float relu_(float v) { return fmaxf(v, 0.f); }
static __device__ __forceinline__ ushort f2bf(float f) {
    __bf16 h = (__bf16)f;
    ushort r;
    __builtin_memcpy(&r, &h, 2);
    return r;
}
static __device__ __forceinline__ bf16x8 cvt8(float4 a, float4 b) {
    bf16x8 r;
    r[0] = (__bf16)a.x; r[1] = (__bf16)a.y; r[2] = (__bf16)a.z; r[3] = (__bf16)a.w;
    r[4] = (__bf16)b.x; r[5] = (__bf16)b.y; r[6] = (__bf16)b.z; r[7] = (__bf16)b.w;
    return r;
}

// ---------------- K0: convert adj -> bf16; back_w*bn2_scale -> bf16 ----------------
__global__ void k_prep(const float* __restrict__ adj, const float* __restrict__ bw,
                       const float* __restrict__ g2, ushort* __restrict__ adjb,
                       ushort* __restrict__ bwb)
{
    int blk = blockIdx.x, t = threadIdx.x;
    if (blk < 1024) {
        int i = (blk * 256 + t) * 4;
        float4 v = *(const float4*)(adj + i);
        ushort4 o;
        o.x = f2bf(v.x); o.y = f2bf(v.y); o.z = f2bf(v.z); o.w = f2bf(v.w);
        *(ushort4*)(adjb + i) = o;
    } else {
        const float rs = 1.f / sqrtf(1.f + EPSV);
        for (int j = t; j < 4096; j += 256) {
            int o = j >> 6;
            bwb[j] = f2bf(bw[j] * g2[o] * rs);
        }
    }
}

// ---------------- K1: softmax over 27 classes + 2x2 maxpool -> P fp32, Pt bf16 ----------------
__global__ void k_softmax_pool(const float* __restrict__ SP, float* __restrict__ P,
                               ushort* __restrict__ Pt)
{
    int tid = blockIdx.x * 256 + threadIdx.x;       // 65536 = B * 1024
    int b = tid >> 10, ol = tid & 1023;
    int oi = ol >> 5, oj = ol & 31;
    float acc[NC_];
#pragma unroll
    for (int c = 0; c < NC_; ++c) acc[c] = 0.f;
    const float* base = SP + (size_t)b * NC_ * 4096;
#pragma unroll
    for (int p = 0; p < 4; ++p) {
        int di = p >> 1, dj = p & 1;
        int off = (2 * oi + di) * 64 + (2 * oj + dj);
        float v[NC_];
        float m = -1e30f;
#pragma unroll
        for (int c = 0; c < NC_; ++c) { v[c] = base[c * 4096 + off]; m = fmaxf(m, v[c]); }
        float s = 0.f;
#pragma unroll
        for (int c = 0; c < NC_; ++c) { v[c] = __expf(v[c] - m); s += v[c]; }
        float inv = 1.f / s;
#pragma unroll
        for (int c = 0; c < NC_; ++c) acc[c] = fmaxf(acc[c], v[c] * inv);
    }
#pragma unroll
    for (int c = 0; c < NC_; ++c)
        P[((size_t)b * NC_ + c) * L_ + ol] = acc[c];
    // transposed bf16 copy, K padded to 32 with zeros: Pt[b][l][c]
    ushort h[32];
#pragma unroll
    for (int c = 0; c < NC_; ++c) h[c] = f2bf(acc[c]);
#pragma unroll
    for (int c = NC_; c < 32; ++c) h[c] = 0;
    ushort* pt = Pt + ((size_t)b * L_ + ol) * 32;
#pragma unroll
    for (int c0 = 0; c0 < 32; c0 += 4)
        *(ushort4*)&pt[c0] = *(ushort4*)&h[c0];
}

// ---------------- K2: MFMA trans: t = relu(BN(x·w^T)) -> y fp32 ; yw = t·w_sp^T -> bf16 ----------------
__global__ __launch_bounds__(256) void k_trans_mfma(
    const float* __restrict__ x, const float* __restrict__ w,
    const float* __restrict__ g, const float* __restrict__ beta,
    const float* __restrict__ w_sp,
    float* __restrict__ y, ushort* __restrict__ ywb)
{
    __shared__ __align__(16) ushort sT[4][32][72];   // per-wave t tile bf16 [l][f]
    const int t = threadIdx.x;
    const int wv = t >> 6, lane = t & 63;
    const int rA = lane & 15, kg = lane >> 4;
    const int b = blockIdx.x >> 3;
    const int l0 = (blockIdx.x & 7) << 7;
    const int wl0 = l0 + wv * 32;

    const float* xb = x + ((size_t)b << 16);

    // MFMA1: t[l][f] = sum_c x[c][l] * w[f][c]
    f32x4 acc[2][4];
#pragma unroll
    for (int i = 0; i < 2; ++i)
#pragma unroll
        for (int j = 0; j < 4; ++j) acc[i][j] = (f32x4){0.f, 0.f, 0.f, 0.f};
#pragma unroll
    for (int ks = 0; ks < 2; ++ks) {
        bf16x8 a[2];
#pragma unroll
        for (int lt = 0; lt < 2; ++lt) {
            const int l = wl0 + lt * 16 + rA;
            bf16x8 av;
#pragma unroll
            for (int j = 0; j < 8; ++j)
                av[j] = (__bf16)xb[(size_t)(ks * 32 + kg * 8 + j) * 1024 + l];
            a[lt] = av;
        }
#pragma unroll
        for (int fc = 0; fc < 4; ++fc) {
            const float* wp = w + (fc * 16 + rA) * 64 + ks * 32 + kg * 8;
            bf16x8 bv = cvt8(*(const float4*)wp, *(const float4*)(wp + 4));
            acc[0][fc] = __builtin_amdgcn_mfma_f32_16x16x32_bf16(a[0], bv, acc[0][fc], 0, 0, 0);
            acc[1][fc] = __builtin_amdgcn_mfma_f32_16x16x32_bf16(a[1], bv, acc[1][fc], 0, 0, 0);
        }
    }

    // epilogue: BN + ReLU ; y fp32 -> global ; t bf16 -> LDS
    const float rs = 1.f / sqrtf(1.f + EPSV);
    float* yg = y + ((size_t)b << 16);
#pragma unroll
    for (int fc = 0; fc < 4; ++fc) {
        const int f = fc * 16 + rA;
        const float sc = g[f] * rs, bb = beta[f];
#pragma unroll
        for (int lt = 0; lt < 2; ++lt) {
            float4 tv;
            float* tp = (float*)&tv;
#pragma unroll
            for (int r = 0; r < 4; ++r) {
                float v = relu_(sc * acc[lt][fc][r] + bb);
                tp[r] = v;
                sT[wv][lt * 16 + kg * 4 + r][f] = f2bf(v);
            }
            *(float4*)(yg + (size_t)f * 1024 + wl0 + lt * 16 + kg * 4) = tv;
        }
    }
    __syncthreads();

    // MFMA2: yw[l][f] = sum_f' t[l][f'] * w_sp[f][f']
    f32x4 acc2[2][4];
#pragma unroll
    for (int i = 0; i < 2; ++i)
#pragma unroll
        for (int j = 0; j < 4; ++j) acc2[i][j] = (f32x4){0.f, 0.f, 0.f, 0.f};
#pragma unroll
    for (int kh = 0; kh < 2; ++kh) {
        bf16x8 a[2];
#pragma unroll
        for (int lt = 0; lt < 2; ++lt)
            a[lt] = *(const bf16x8*)&sT[wv][lt * 16 + rA][kh * 32 + kg * 8];
#pragma unroll
        for (int fc = 0; fc < 4; ++fc) {
            const float* wp = w_sp + (fc * 16 + rA) * 64 + kh * 32 + kg * 8;
            bf16x8 bv = cvt8(*(const float4*)wp, *(const float4*)(wp + 4));
            acc2[0][fc] = __builtin_amdgcn_mfma_f32_16x16x32_bf16(a[0], bv, acc2[0][fc], 0, 0, 0);
            acc2[1][fc] = __builtin_amdgcn_mfma_f32_16x16x32_bf16(a[1], bv, acc2[1][fc], 0, 0, 0);
        }
    }
    ushort* yp = ywb + ((size_t)b << 16);
#pragma unroll
    for (int fc = 0; fc < 4; ++fc) {
        const int f = fc * 16 + rA;
#pragma unroll
        for (int lt = 0; lt < 2; ++lt) {
            ushort4 ov;
            ov.x = f2bf(acc2[lt][fc][0]);
            ov.y = f2bf(acc2[lt][fc][1]);
            ov.z = f2bf(acc2[lt][fc][2]);
            ov.w = f2bf(acc2[lt][fc][3]);
            *(ushort4*)(yp + (size_t)f * 1024 + wl0 + lt * 16 + kg * 4) = ov;
        }
    }
}

// ---------------- K3: partial yn/U over one 64-length L-tile per block ----------------
// grid = B * NCHUNK ; partYN/partU[bid][c*64+f], c in [0,27)
__global__ __launch_bounds__(256) void k_yn_U_part(
    const float* __restrict__ y, const float* __restrict__ P,
    const float* __restrict__ w_nc,
    float* __restrict__ partYN, float* __restrict__ partU)
{
    __shared__ __align__(16) float ylds[64 * 68];
    __shared__ __align__(16) float plds[NC_ * 68];
    __shared__ __align__(16) float wlds[NC_ * 68];
    const int t = threadIdx.x;                      // 256
    const int b  = blockIdx.x >> 4;
    const int l0 = (blockIdx.x & 15) << 6;
    const int f = t & 63;
    const int q = t >> 6;                           // 0..3 (wave-uniform)
    const float* yb = y + ((size_t)b << 16);
    const float* Pb = P + (size_t)b * NC_ * L_;
    for (int idx = t; idx < 4096; idx += 256) {
        int ff = idx >> 6, lc = idx & 63;
        ylds[ff * 68 + lc] = yb[(size_t)ff * L_ + l0 + lc];
    }
    for (int idx = t; idx < NC_ * 64; idx += 256) {
        int c = idx >> 6, lc = idx & 63;
        plds[c * 68 + lc] = Pb[(size_t)c * L_ + l0 + lc];
        wlds[c * 68 + lc] = w_nc[(size_t)c * L_ + l0 + lc];
    }
    __syncthreads();
    float pyn[7], pU[7];
#pragma unroll
    for (int r = 0; r < 7; ++r) { pyn[r] = 0.f; pU[r] = 0.f; }
#pragma unroll 4
    for (int l4 = 0; l4 < 16; ++l4) {
        float4 y4 = *(const float4*)&ylds[f * 68 + l4 * 4];
        const float ya[4] = {y4.x, y4.y, y4.z, y4.w};
#pragma unroll
        for (int r = 0; r < 7; ++r) {
            int c = q + (r << 2);
            if (c < NC_) {
#pragma unroll
                for (int i = 0; i < 4; ++i) {
                    int l = l4 * 4 + i;
                    pyn[r] = fmaf(wlds[c * 68 + l], ya[i], pyn[r]);
                    pU[r]  = fmaf(plds[c * 68 + l], ya[i], pU[r]);
                }
            }
        }
    }
    float* oy = partYN + (size_t)blockIdx.x * (NC_ * 64);
    float* ou = partU  + (size_t)blockIdx.x * (NC_ * 64);
#pragma unroll
    for (int r = 0; r < 7; ++r) {
        int c = q + (r << 2);
        if (c < NC_) {
            oy[c * 64 + f] = pyn[r];
            ou[c * 64 + f] = pU[r];
        }
    }
}

// ---------------- K4: reduce partials; sigma = yn·w_kc^T + b_kc ; Z = sigma·U ; Zwt bf16 ----------------
__global__ void k_sigma_Z(const float* __restrict__ partYN, const float* __restrict__ partU,
                          const float* __restrict__ b_nc,
                          const float* __restrict__ w_kc, const float* __restrict__ b_kc,
                          const float* __restrict__ w_g, ushort* __restrict__ Zwt)
{
    __shared__ float syn[F_ * NC_];     // [f][c]
    __shared__ float su[NC_ * F_];      // [k][f]
    __shared__ float swk[NC_ * F_];     // [k][f]
    __shared__ float ssig[NC_ * NC_];   // [c][k]
    __shared__ float sz[NC_ * F_];      // Z [c][f]
    __shared__ float swg[F_ * F_];      // w_g [f][f']
    const int t = threadIdx.x;          // 256
    const int b = blockIdx.x;
    // reduce partials: idx = c*64 + f
    for (int idx = t; idx < NC_ * F_; idx += 256) {
        int c = idx >> 6, f = idx & 63;
        float sy = 0.f, suv = 0.f;
        const float* py = partYN + ((size_t)b * NCHUNK) * (NC_ * 64) + idx;
        const float* pu = partU  + ((size_t)b * NCHUNK) * (NC_ * 64) + idx;
#pragma unroll
        for (int p = 0; p < NCHUNK; ++p) {
            sy  += py[p * (NC_ * 64)];
            suv += pu[p * (NC_ * 64)];
        }
        syn[f * NC_ + c] = sy + b_nc[c];
        su[c * F_ + f]   = suv;
    }
    for (int idx = t; idx < NC_ * F_; idx += 256) swk[idx] = w_kc[idx];
    for (int idx = t; idx < F_ * F_; idx += 256) swg[idx] = w_g[idx];
    __syncthreads();
    for (int idx = t; idx < NC_ * NC_; idx += 256) {
        int c = idx / NC_, k = idx - c * NC_;
        float s = b_kc[k];
        for (int ff = 0; ff < F_; ++ff)
            s = fmaf(syn[ff * NC_ + c], swk[k * F_ + ff], s);
        ssig[c * NC_ + k] = s;
    }
    __syncthreads();
    for (int idx = t; idx < NC_ * F_; idx += 256) {
        int c = idx >> 6, ff = idx & 63;
        float s = 0.f;
        for (int k = 0; k < NC_; ++k)
            s = fmaf(ssig[c * NC_ + k], su[k * F_ + ff], s);
        sz[idx] = s;
    }
    __syncthreads();
    // Zw[c][f] = sum_f' Z[c][f'] * w_g[f][f'] ; store transposed [f][c], c padded to 32
    for (int idx = t; idx < F_ * 32; idx += 256) {
        int f = idx >> 5, c = idx & 31;
        float s = 0.f;
        if (c < NC_)
            for (int fp = 0; fp < F_; ++fp)
                s = fmaf(sz[c * F_ + fp], swg[f * F_ + fp], s);
        Zwt[(size_t)b * F_ * 32 + idx] = f2bf(s);
    }
}

// ---------------- K5: MFMA fused: S=adj·yw^T (K=1024, yw LDS-staged), D, epilogue, back conv ----------------
__global__ __launch_bounds__(256, 2) void k_fused2(
    const ushort* __restrict__ adjb_, const ushort* __restrict__ ywb_,
    const ushort* __restrict__ Pt_, const ushort* __restrict__ Zwt_,
    const float* __restrict__ y, const float* __restrict__ b_g,
    const float* __restrict__ b_sp, const ushort* __restrict__ bwb_,
    const float* __restrict__ bn2b, float* __restrict__ out)
{
    // 64 KB pool: sYW [64 f][512 m] bf16 (one K-half, XOR-swizzled chunks);
    // after the main loop it is reused as sPre [4*32][68] fp32.
    __shared__ __align__(16) char pool[65536];
    ushort* sYW = (ushort*)pool;
    float*  sPre = (float*)pool;

    const int t = threadIdx.x;
    const int w = t >> 6, lane = t & 63;
    const int rA = lane & 15, kg = lane >> 4;
    const int fr = rA & 7;                          // row&7 for the XOR swizzle
    const int b = blockIdx.x >> 3;
    const int l0 = (blockIdx.x & 7) << 7;           // 128-row tile
    const int wl0 = l0 + w * 32;                    // this wave's 32 rows

    const __bf16* adjb = (const __bf16*)adjb_;
    const __bf16* ywb  = (const __bf16*)ywb_ + ((size_t)b << 16);
    const __bf16* Ptb  = (const __bf16*)Pt_  + ((size_t)b << 15);
    const __bf16* Zwtb = (const __bf16*)Zwt_ + ((size_t)b << 11);
    const __bf16* bwb  = (const __bf16*)bwb_;

    f32x4 accS[2][4];
#pragma unroll
    for (int i = 0; i < 2; ++i)
#pragma unroll
        for (int j = 0; j < 4; ++j) accS[i][j] = (f32x4){0.f, 0.f, 0.f, 0.f};

    // main GEMM: S[l][f] = sum_m adj[l][m] * yw[f][m], two 512-wide K-halves
    const __bf16* pa = adjb + (size_t)(wl0 + rA) * 1024 + kg * 8;
#pragma unroll 1
    for (int half = 0; half < 2; ++half) {
        // stage yw[0..63][half*512 .. +512) into LDS, chunk-swizzled: chunk' = chunk ^ (f&7)
#pragma unroll
        for (int i = 0; i < 16; ++i) {
            int q = i * 256 + t;                    // 4096 chunks of 16B
            int f = q >> 6, cm = q & 63;
            bf16x8 v = *(const bf16x8*)(ywb + (size_t)f * 1024 + half * 512 + cm * 8);
            *(bf16x8*)&sYW[f * 512 + ((cm ^ (f & 7)) << 3)] = v;
        }
        __syncthreads();
#pragma unroll 8
        for (int ksl = 0; ksl < 16; ++ksl) {
            const int ks = half * 16 + ksl;
            bf16x8 a0 = *(const bf16x8*)(pa + ks * 32);
            bf16x8 a1 = *(const bf16x8*)(pa + 16 * 1024 + ks * 32);
            const int ch = ((kg + ksl * 4) ^ fr) << 3;
            bf16x8 f0 = *(const bf16x8*)&sYW[(0 * 16 + rA) * 512 + ch];
            bf16x8 f1 = *(const bf16x8*)&sYW[(1 * 16 + rA) * 512 + ch];
            bf16x8 f2 = *(const bf16x8*)&sYW[(2 * 16 + rA) * 512 + ch];
            bf16x8 f3 = *(const bf16x8*)&sYW[(3 * 16 + rA) * 512 + ch];
            accS[0][0] = __builtin_amdgcn_mfma_f32_16x16x32_bf16(a0, f0, accS[0][0], 0, 0, 0);
            accS[0][1] = __builtin_amdgcn_mfma_f32_16x16x32_bf16(a0, f1, accS[0][1], 0, 0, 0);
            accS[0][2] = __builtin_amdgcn_mfma_f32_16x16x32_bf16(a0, f2, accS[0][2], 0, 0, 0);
            accS[0][3] = __builtin_amdgcn_mfma_f32_16x16x32_bf16(a0, f3, accS[0][3], 0, 0, 0);
            accS[1][0] = __builtin_amdgcn_mfma_f32_16x16x32_bf16(a1, f0, accS[1][0], 0, 0, 0);
            accS[1][1] = __builtin_amdgcn_mfma_f32_16x16x32_bf16(a1, f1, accS[1][1], 0, 0, 0);
            accS[1][2] = __builtin_amdgcn_mfma_f32_16x16x32_bf16(a1, f2, accS[1][2], 0, 0, 0);
            accS[1][3] = __builtin_amdgcn_mfma_f32_16x16x32_bf16(a1, f3, accS[1][3], 0, 0, 0);
        }
        __syncthreads();
    }

    // dynamic path: D[l][f] = sum_c Pt[l][c] * Zwt[f][c], K=32 (c padded)
    f32x4 accD[2][4];
#pragma unroll
    for (int i = 0; i < 2; ++i)
#pragma unroll
        for (int j = 0; j < 4; ++j) accD[i][j] = (f32x4){0.f, 0.f, 0.f, 0.f};
    {
        const __bf16* qa = Ptb + (size_t)(wl0 + rA) * 32 + kg * 8;
        bf16x8 a0 = *(const bf16x8*)(qa);
        bf16x8 a1 = *(const bf16x8*)(qa + 16 * 32);
        const __bf16* qb = Zwtb + (size_t)rA * 32 + kg * 8;
        bf16x8 z0 = *(const bf16x8*)(qb + 0 * 512);
        bf16x8 z1 = *(const bf16x8*)(qb + 1 * 512);
        bf16x8 z2 = *(const bf16x8*)(qb + 2 * 512);
        bf16x8 z3 = *(const bf16x8*)(qb + 3 * 512);
        accD[0][0] = __builtin_amdgcn_mfma_f32_16x16x32_bf16(a0, z0, accD[0][0], 0, 0, 0);
        accD[0][1] = __builtin_amdgcn_mfma_f32_16x16x32_bf16(a0, z1, accD[0][1], 0, 0, 0);
        accD[0][2] = __builtin_amdgcn_mfma_f32_16x16x32_bf16(a0, z2, accD[0][2], 0, 0, 0);
        accD[0][3] = __builtin_amdgcn_mfma_f32_16x16x32_bf16(a0, z3, accD[0][3], 0, 0, 0);
        accD[1][0] = __builtin_amdgcn_mfma_f32_16x16x32_bf16(a1, z0, accD[1][0], 0, 0, 0);
        accD[1][1] = __builtin_amdgcn_mfma_f32_16x16x32_bf16(a1, z1, accD[1][1], 0, 0, 0);
        accD[1][2] = __builtin_amdgcn_mfma_f32_16x16x32_bf16(a1, z2, accD[1][2], 0, 0, 0);
        accD[1][3] = __builtin_amdgcn_mfma_f32_16x16x32_bf16(a1, z3, accD[1][3], 0, 0, 0);
    }

    // epilogue: pre = relu(D + b_g) + relu(S + b_sp) + 3*y  -> LDS (fp32, pad 68)
    float bg4[4], bs4[4];
#pragma unroll
    for (int fc = 0; fc < 4; ++fc) { bg4[fc] = b_g[fc * 16 + rA]; bs4[fc] = b_sp[fc * 16 + rA]; }
    const float* yb = y + ((size_t)b << 16);
    const int wOff = w * 32 * 68;
#pragma unroll
    for (int lt = 0; lt < 2; ++lt) {
        int lbase = wl0 + lt * 16 + kg * 4;
        int row = lt * 16 + kg * 4;
#pragma unroll
        for (int fc = 0; fc < 4; ++fc) {
            int f = fc * 16 + rA;
            float4 yv = *(const float4*)(yb + (size_t)f * 1024 + lbase);
            f32x4 s = accS[lt][fc], d = accD[lt][fc];
            sPre[wOff + (row + 0) * 68 + f] = relu_(d[0] + bg4[fc]) + relu_(s[0] + bs4[fc]) + 3.f * yv.x;
            sPre[wOff + (row + 1) * 68 + f] = relu_(d[1] + bg4[fc]) + relu_(s[1] + bs4[fc]) + 3.f * yv.y;
            sPre[wOff + (row + 2) * 68 + f] = relu_(d[2] + bg4[fc]) + relu_(s[2] + bs4[fc]) + 3.f * yv.z;
            sPre[wOff + (row + 3) * 68 + f] = relu_(d[3] + bg4[fc]) + relu_(s[3] + bs4[fc]) + 3.f * yv.w;
        }
    }
    __syncthreads();

    // back conv: out[o][l] = relu( sum_f pre[l][f] * bwb[o][f] + bn2b[o] )
    f32x4 accO[2][4];
#pragma unroll
    for (int i = 0; i < 2; ++i)
#pragma unroll
        for (int j = 0; j < 4; ++j) accO[i][j] = (f32x4){0.f, 0.f, 0.f, 0.f};
#pragma unroll
    for (int kh = 0; kh < 2; ++kh) {
        bf16x8 af[2];
#pragma unroll
        for (int lt = 0; lt < 2; ++lt) {
            int off = wOff + (lt * 16 + rA) * 68 + kh * 32 + kg * 8;
            float4 u0 = *(const float4*)&sPre[off];
            float4 u1 = *(const float4*)&sPre[off + 4];
            bf16x8 a;
            a[0] = (__bf16)u0.x; a[1] = (__bf16)u0.y; a[2] = (__bf16)u0.z; a[3] = (__bf16)u0.w;
            a[4] = (__bf16)u1.x; a[5] = (__bf16)u1.y; a[6] = (__bf16)u1.z; a[7] = (__bf16)u1.w;
            af[lt] = a;
        }
#pragma unroll
        for (int oc = 0; oc < 4; ++oc) {
            bf16x8 bo = *(const bf16x8*)(bwb + oc * 1024 + (size_t)rA * 64 + kh * 32 + kg * 8);
            accO[0][oc] = __builtin_amdgcn_mfma_f32_16x16x32_bf16(af[0], bo, accO[0][oc], 0, 0, 0);
            accO[1][oc] = __builtin_amdgcn_mfma_f32_16x16x32_bf16(af[1], bo, accO[1][oc], 0, 0, 0);
        }
    }
    float* ob = out + ((size_t)b << 16);
#pragma unroll
    for (int oc = 0; oc < 4; ++oc) {
        float b2v = bn2b[oc * 16 + rA];
#pragma unroll
        for (int lt = 0; lt < 2; ++lt) {
            float4 ov = make_float4(accO[lt][oc][0] + b2v, accO[lt][oc][1] + b2v,
                                    accO[lt][oc][2] + b2v, accO[lt][oc][3] + b2v);
            ov.x = relu_(ov.x); ov.y = relu_(ov.y); ov.z = relu_(ov.z); ov.w = relu_(ov.w);
            *(float4*)(ob + (size_t)(oc * 16 + rA) * 1024 + wl0 + lt * 16 + kg * 4) = ov;
        }
    }
}

extern "C" void kernel_launch(void* const* d_in, const int* in_sizes, int n_in,
                              void* d_out, int out_size, void* d_ws, size_t ws_size,
                              hipStream_t stream)
{
    const float* x       = (const float*)d_in[0];
    const float* SP      = (const float*)d_in[1];
    const float* trans_w = (const float*)d_in[2];
    const float* bn1_g   = (const float*)d_in[3];
    const float* bn1_b   = (const float*)d_in[4];
    const float* w_nc    = (const float*)d_in[5];
    const float* b_nc    = (const float*)d_in[6];
    const float* w_kc    = (const float*)d_in[7];
    const float* b_kc    = (const float*)d_in[8];
    const float* w_g     = (const float*)d_in[9];
    const float* b_g     = (const float*)d_in[10];
    const float* adj     = (const float*)d_in[11];
    const float* w_sp    = (const float*)d_in[12];
    const float* b_sp    = (const float*)d_in[13];
    const float* back_w  = (const float*)d_in[14];
    const float* bn2_g   = (const float*)d_in[15];
    const float* bn2_b   = (const float*)d_in[16];
    float* out = (float*)d_out;

    float* ws = (float*)d_ws;
    float* P      = ws;                                     // [64][27][1024] fp32
    float* y      = P + (size_t)B_ * NC_ * L_;              // [64][64][1024] fp32
    float* partYN = y + (size_t)B_ * F_ * L_;               // [B*16][27*64] fp32
    float* partU  = partYN + (size_t)B_ * NCHUNK * NC_ * F_;// [B*16][27*64] fp32
    ushort* Pt   = (ushort*)(partU + (size_t)B_ * NCHUNK * NC_ * F_); // [64][1024][32] bf16
    ushort* Zwt  = Pt   + (size_t)B_ * L_ * 32;             // [64][64][32] bf16
    ushort* ywb  = Zwt  + (size_t)B_ * F_ * 32;             // [64][64][1024] bf16
    ushort* adjb = ywb  + (size_t)B_ * F_ * L_;             // [1024][1024] bf16
    ushort* bwb  = adjb + (size_t)L_ * L_;                  // [64][64] bf16

    k_prep<<<1025, 256, 0, stream>>>(adj, back_w, bn2_g, adjb, bwb);
    k_softmax_pool<<<256, 256, 0, stream>>>(SP, P, Pt);
    k_trans_mfma<<<512, 256, 0, stream>>>(x, trans_w, bn1_g, bn1_b, w_sp, y, ywb);
    k_yn_U_part<<<B_ * NCHUNK, 256, 0, stream>>>(y, P, w_nc, partYN, partU);
    k_sigma_Z<<<64, 256, 0, stream>>>(partYN, partU, b_nc, w_kc, b_kc, w_g, Zwt);
    k_fused2<<<512, 256, 0, stream>>>(adjb, ywb, Pt, Zwt, y, b_g, b_sp, bwb, bn2_b, out);
}

// Round 6
// 104.618 us; speedup vs baseline: 3.9088x; 1.0868x over previous
//
#include <hip/hip_runtime.h>

#define B_  64
#define F_  64
#define NC_ 27
#define L_  1024
#define EPSV 1e-5f
#define NCHUNK 16

typedef __bf16 bf16x8 __attribute__((ext_vector_type(8)));
typedef float  f32x4  __attribute__((ext_vector_type(4)));

static __device__ __forceinline__ float relu_(float v) { return fmaxf(v, 0.f); }
static __device__ __forceinline__ ushort f2bf(float f) {
    __bf16 h = (__bf16)f;
    ushort r;
    __builtin_memcpy(&r, &h, 2);
    return r;
}
static __device__ __forceinline__ float bf2f(ushort u) {
    __bf16 h;
    __builtin_memcpy(&h, &u, 2);
    return (float)h;
}
static __device__ __forceinline__ bf16x8 cvt8(float4 a, float4 b) {
    bf16x8 r;
    r[0] = (__bf16)a.x; r[1] = (__bf16)a.y; r[2] = (__bf16)a.z; r[3] = (__bf16)a.w;
    r[4] = (__bf16)b.x; r[5] = (__bf16)b.y; r[6] = (__bf16)b.z; r[7] = (__bf16)b.w;
    return r;
}

// ---------------- K1: softmax+pool (coalesced float2) -> Pcb bf16 [b][c][l], Pt bf16 [b][l][32]
//                  + adj -> bf16 ; back_w*bn2_scale -> bf16   (merged prep, disjoint blocks)
__global__ __launch_bounds__(256) void k_softmax_prep(
    const float* __restrict__ SP, const float* __restrict__ adj,
    const float* __restrict__ bw, const float* __restrict__ g2,
    ushort* __restrict__ Pcb, ushort* __restrict__ Pt,
    ushort* __restrict__ adjb, ushort* __restrict__ bwb)
{
    const int blk = blockIdx.x, t = threadIdx.x;
    if (blk >= 256) {
        if (blk < 1280) {
            int i = (((blk - 256) << 8) + t) << 2;
            float4 v = *(const float4*)(adj + i);
            ushort4 o;
            o.x = f2bf(v.x); o.y = f2bf(v.y); o.z = f2bf(v.z); o.w = f2bf(v.w);
            *(ushort4*)(adjb + i) = o;
        } else {
            const float rs = 1.f / sqrtf(1.f + EPSV);
            for (int j = t; j < 4096; j += 256) {
                int o = j >> 6;
                bwb[j] = f2bf(bw[j] * g2[o] * rs);
            }
        }
        return;
    }
    int tid = blk * 256 + t;                    // 65536 = B * 1024
    int b = tid >> 10, ol = tid & 1023;
    int oi = ol >> 5, oj = ol & 31;
    float acc[NC_];
#pragma unroll
    for (int c = 0; c < NC_; ++c) acc[c] = 0.f;
    const float* base = SP + (size_t)b * NC_ * 4096 + 2 * oj;
#pragma unroll
    for (int di = 0; di < 2; ++di) {
        const float* rp = base + (2 * oi + di) * 64;
        float v0[NC_], v1[NC_];
        float m0 = -1e30f, m1 = -1e30f;
#pragma unroll
        for (int c = 0; c < NC_; ++c) {
            float2 v = *(const float2*)(rp + c * 4096);
            v0[c] = v.x; v1[c] = v.y;
            m0 = fmaxf(m0, v.x); m1 = fmaxf(m1, v.y);
        }
        float s0 = 0.f, s1 = 0.f;
#pragma unroll
        for (int c = 0; c < NC_; ++c) {
            v0[c] = __expf(v0[c] - m0); s0 += v0[c];
            v1[c] = __expf(v1[c] - m1); s1 += v1[c];
        }
        float i0 = 1.f / s0, i1 = 1.f / s1;
#pragma unroll
        for (int c = 0; c < NC_; ++c)
            acc[c] = fmaxf(acc[c], fmaxf(v0[c] * i0, v1[c] * i1));
    }
    ushort h[32];
#pragma unroll
    for (int c = 0; c < NC_; ++c) {
        h[c] = f2bf(acc[c]);
        Pcb[((size_t)b * NC_ + c) * L_ + ol] = h[c];
    }
#pragma unroll
    for (int c = NC_; c < 32; ++c) h[c] = 0;
    ushort* pt = Pt + ((size_t)b * L_ + ol) * 32;
#pragma unroll
    for (int c0 = 0; c0 < 32; c0 += 4)
        *(ushort4*)&pt[c0] = *(ushort4*)&h[c0];
}

// ---------------- K2: MFMA trans: t = relu(BN(x·w^T)) -> yb16 ; yw = t·w_sp^T -> bf16 ----------------
__global__ __launch_bounds__(256) void k_trans_mfma(
    const float* __restrict__ x, const float* __restrict__ w,
    const float* __restrict__ g, const float* __restrict__ beta,
    const float* __restrict__ w_sp,
    ushort* __restrict__ yb16, ushort* __restrict__ ywb)
{
    __shared__ __align__(16) ushort sT[4][32][72];   // per-wave t tile bf16 [l][f]
    const int t = threadIdx.x;
    const int wv = t >> 6, lane = t & 63;
    const int rA = lane & 15, kg = lane >> 4;
    const int b = blockIdx.x >> 3;
    const int l0 = (blockIdx.x & 7) << 7;
    const int wl0 = l0 + wv * 32;

    const float* xb = x + ((size_t)b << 16);

    // MFMA1: t[l][f] = sum_c x[c][l] * w[f][c]
    f32x4 acc[2][4];
#pragma unroll
    for (int i = 0; i < 2; ++i)
#pragma unroll
        for (int j = 0; j < 4; ++j) acc[i][j] = (f32x4){0.f, 0.f, 0.f, 0.f};
#pragma unroll
    for (int ks = 0; ks < 2; ++ks) {
        bf16x8 a[2];
#pragma unroll
        for (int lt = 0; lt < 2; ++lt) {
            const int l = wl0 + lt * 16 + rA;
            bf16x8 av;
#pragma unroll
            for (int j = 0; j < 8; ++j)
                av[j] = (__bf16)xb[(size_t)(ks * 32 + kg * 8 + j) * 1024 + l];
            a[lt] = av;
        }
#pragma unroll
        for (int fc = 0; fc < 4; ++fc) {
            const float* wp = w + (fc * 16 + rA) * 64 + ks * 32 + kg * 8;
            bf16x8 bv = cvt8(*(const float4*)wp, *(const float4*)(wp + 4));
            acc[0][fc] = __builtin_amdgcn_mfma_f32_16x16x32_bf16(a[0], bv, acc[0][fc], 0, 0, 0);
            acc[1][fc] = __builtin_amdgcn_mfma_f32_16x16x32_bf16(a[1], bv, acc[1][fc], 0, 0, 0);
        }
    }

    // epilogue: BN + ReLU ; t bf16 -> global (yb16) + LDS
    const float rs = 1.f / sqrtf(1.f + EPSV);
    ushort* yg = yb16 + ((size_t)b << 16);
#pragma unroll
    for (int fc = 0; fc < 4; ++fc) {
        const int f = fc * 16 + rA;
        const float sc = g[f] * rs, bb = beta[f];
#pragma unroll
        for (int lt = 0; lt < 2; ++lt) {
            ushort4 tv;
            ushort* tp = (ushort*)&tv;
#pragma unroll
            for (int r = 0; r < 4; ++r) {
                float v = relu_(sc * acc[lt][fc][r] + bb);
                tp[r] = f2bf(v);
                sT[wv][lt * 16 + kg * 4 + r][f] = tp[r];
            }
            *(ushort4*)(yg + (size_t)f * 1024 + wl0 + lt * 16 + kg * 4) = tv;
        }
    }
    __syncthreads();

    // MFMA2: yw[l][f] = sum_f' t[l][f'] * w_sp[f][f']
    f32x4 acc2[2][4];
#pragma unroll
    for (int i = 0; i < 2; ++i)
#pragma unroll
        for (int j = 0; j < 4; ++j) acc2[i][j] = (f32x4){0.f, 0.f, 0.f, 0.f};
#pragma unroll
    for (int kh = 0; kh < 2; ++kh) {
        bf16x8 a[2];
#pragma unroll
        for (int lt = 0; lt < 2; ++lt)
            a[lt] = *(const bf16x8*)&sT[wv][lt * 16 + rA][kh * 32 + kg * 8];
#pragma unroll
        for (int fc = 0; fc < 4; ++fc) {
            const float* wp = w_sp + (fc * 16 + rA) * 64 + kh * 32 + kg * 8;
            bf16x8 bv = cvt8(*(const float4*)wp, *(const float4*)(wp + 4));
            acc2[0][fc] = __builtin_amdgcn_mfma_f32_16x16x32_bf16(a[0], bv, acc2[0][fc], 0, 0, 0);
            acc2[1][fc] = __builtin_amdgcn_mfma_f32_16x16x32_bf16(a[1], bv, acc2[1][fc], 0, 0, 0);
        }
    }
    ushort* yp = ywb + ((size_t)b << 16);
#pragma unroll
    for (int fc = 0; fc < 4; ++fc) {
        const int f = fc * 16 + rA;
#pragma unroll
        for (int lt = 0; lt < 2; ++lt) {
            ushort4 ov;
            ov.x = f2bf(acc2[lt][fc][0]);
            ov.y = f2bf(acc2[lt][fc][1]);
            ov.z = f2bf(acc2[lt][fc][2]);
            ov.w = f2bf(acc2[lt][fc][3]);
            *(ushort4*)(yp + (size_t)f * 1024 + wl0 + lt * 16 + kg * 4) = ov;
        }
    }
}

// ---------------- K3: partial yn/U over one 64-length L-tile per block (bf16 inputs) ----------------
__global__ __launch_bounds__(256) void k_yn_U_part(
    const ushort* __restrict__ yb16, const ushort* __restrict__ Pcb,
    const float* __restrict__ w_nc,
    float* __restrict__ partYN, float* __restrict__ partU)
{
    __shared__ __align__(16) float ylds[64 * 68];
    __shared__ __align__(16) float plds[NC_ * 68];
    __shared__ __align__(16) float wlds[NC_ * 68];
    const int t = threadIdx.x;                      // 256
    const int b  = blockIdx.x >> 4;
    const int l0 = (blockIdx.x & 15) << 6;
    const int f = t & 63;
    const int q = t >> 6;                           // 0..3 (wave-uniform)
    const ushort* yb = yb16 + ((size_t)b << 16);
    const ushort* Pb = Pcb + (size_t)b * NC_ * L_;
    for (int idx = t; idx < 1024; idx += 256) {     // y tile: 64f x 16 quads
        int ff = idx >> 4, lc = (idx & 15) << 2;
        ushort4 u = *(const ushort4*)&yb[(size_t)ff * L_ + l0 + lc];
        ylds[ff * 68 + lc + 0] = bf2f(u.x);
        ylds[ff * 68 + lc + 1] = bf2f(u.y);
        ylds[ff * 68 + lc + 2] = bf2f(u.z);
        ylds[ff * 68 + lc + 3] = bf2f(u.w);
    }
    for (int idx = t; idx < NC_ * 16; idx += 256) { // P/w tiles: 27 x 16 quads
        int c = idx >> 4, lc = (idx & 15) << 2;
        ushort4 u = *(const ushort4*)&Pb[(size_t)c * L_ + l0 + lc];
        plds[c * 68 + lc + 0] = bf2f(u.x);
        plds[c * 68 + lc + 1] = bf2f(u.y);
        plds[c * 68 + lc + 2] = bf2f(u.z);
        plds[c * 68 + lc + 3] = bf2f(u.w);
        float4 wv = *(const float4*)&w_nc[(size_t)c * L_ + l0 + lc];
        *(float4*)&wlds[c * 68 + lc] = wv;
    }
    __syncthreads();
    float pyn[7], pU[7];
#pragma unroll
    for (int r = 0; r < 7; ++r) { pyn[r] = 0.f; pU[r] = 0.f; }
#pragma unroll 4
    for (int l4 = 0; l4 < 16; ++l4) {
        float4 y4 = *(const float4*)&ylds[f * 68 + l4 * 4];
        const float ya[4] = {y4.x, y4.y, y4.z, y4.w};
#pragma unroll
        for (int r = 0; r < 7; ++r) {
            int c = q + (r << 2);
            if (c < NC_) {
#pragma unroll
                for (int i = 0; i < 4; ++i) {
                    int l = l4 * 4 + i;
                    pyn[r] = fmaf(wlds[c * 68 + l], ya[i], pyn[r]);
                    pU[r]  = fmaf(plds[c * 68 + l], ya[i], pU[r]);
                }
            }
        }
    }
    float* oy = partYN + (size_t)blockIdx.x * (NC_ * 64);
    float* ou = partU  + (size_t)blockIdx.x * (NC_ * 64);
#pragma unroll
    for (int r = 0; r < 7; ++r) {
        int c = q + (r << 2);
        if (c < NC_) {
            oy[c * 64 + f] = pyn[r];
            ou[c * 64 + f] = pU[r];
        }
    }
}

// ---------------- K4: reduce partials; sigma = yn·w_kc^T + b_kc ; Z = sigma·U ; Zwt bf16 ----------------
__global__ void k_sigma_Z(const float* __restrict__ partYN, const float* __restrict__ partU,
                          const float* __restrict__ b_nc,
                          const float* __restrict__ w_kc, const float* __restrict__ b_kc,
                          const float* __restrict__ w_g, ushort* __restrict__ Zwt)
{
    __shared__ float syn[F_ * NC_];     // [f][c]
    __shared__ float su[NC_ * F_];      // [k][f]
    __shared__ float swk[NC_ * F_];     // [k][f]
    __shared__ float ssig[NC_ * NC_];   // [c][k]
    __shared__ float sz[NC_ * F_];      // Z [c][f]
    __shared__ float swg[F_ * F_];      // w_g [f][f']
    const int t = threadIdx.x;          // 256
    const int b = blockIdx.x;
    for (int idx = t; idx < NC_ * F_; idx += 256) {
        int c = idx >> 6, f = idx & 63;
        float sy = 0.f, suv = 0.f;
        const float* py = partYN + ((size_t)b * NCHUNK) * (NC_ * 64) + idx;
        const float* pu = partU  + ((size_t)b * NCHUNK) * (NC_ * 64) + idx;
#pragma unroll
        for (int p = 0; p < NCHUNK; ++p) {
            sy  += py[p * (NC_ * 64)];
            suv += pu[p * (NC_ * 64)];
        }
        syn[f * NC_ + c] = sy + b_nc[c];
        su[c * F_ + f]   = suv;
    }
    for (int idx = t; idx < NC_ * F_; idx += 256) swk[idx] = w_kc[idx];
    for (int idx = t; idx < F_ * F_; idx += 256) swg[idx] = w_g[idx];
    __syncthreads();
    for (int idx = t; idx < NC_ * NC_; idx += 256) {
        int c = idx / NC_, k = idx - c * NC_;
        float s = b_kc[k];
        for (int ff = 0; ff < F_; ++ff)
            s = fmaf(syn[ff * NC_ + c], swk[k * F_ + ff], s);
        ssig[c * NC_ + k] = s;
    }
    __syncthreads();
    for (int idx = t; idx < NC_ * F_; idx += 256) {
        int c = idx >> 6, ff = idx & 63;
        float s = 0.f;
        for (int k = 0; k < NC_; ++k)
            s = fmaf(ssig[c * NC_ + k], su[k * F_ + ff], s);
        sz[idx] = s;
    }
    __syncthreads();
    for (int idx = t; idx < F_ * 32; idx += 256) {
        int f = idx >> 5, c = idx & 31;
        float s = 0.f;
        if (c < NC_)
            for (int fp = 0; fp < F_; ++fp)
                s = fmaf(sz[c * F_ + fp], swg[f * F_ + fp], s);
        Zwt[(size_t)b * F_ * 32 + idx] = f2bf(s);
    }
}

// ---------------- K5: MFMA fused: S=adj·yw^T (LDS-staged, async prefetch), D, epilogue, back conv ----
__global__ __launch_bounds__(256, 2) void k_fused2(
    const ushort* __restrict__ adjb_, const ushort* __restrict__ ywb_,
    const ushort* __restrict__ Pt_, const ushort* __restrict__ Zwt_,
    const ushort* __restrict__ yb16, const float* __restrict__ b_g,
    const float* __restrict__ b_sp, const ushort* __restrict__ bwb_,
    const float* __restrict__ bn2b, float* __restrict__ out)
{
    // 64 KB pool: sYW [64 f][512 m] bf16 (one K-half, XOR-swizzled chunks);
    // reused afterwards as sPre [4*32][68] fp32.
    __shared__ __align__(16) char pool[65536];
    ushort* sYW = (ushort*)pool;
    float*  sPre = (float*)pool;

    const int t = threadIdx.x;
    const int w = t >> 6, lane = t & 63;
    const int rA = lane & 15, kg = lane >> 4;
    const int fr = rA & 7;
    const int b = blockIdx.x >> 3;
    const int l0 = (blockIdx.x & 7) << 7;
    const int wl0 = l0 + w * 32;

    const __bf16* adjb = (const __bf16*)adjb_;
    const __bf16* ywb  = (const __bf16*)ywb_ + ((size_t)b << 16);
    const __bf16* Ptb  = (const __bf16*)Pt_  + ((size_t)b << 15);
    const __bf16* Zwtb = (const __bf16*)Zwt_ + ((size_t)b << 11);
    const __bf16* bwb  = (const __bf16*)bwb_;

    f32x4 accS[2][4];
#pragma unroll
    for (int i = 0; i < 2; ++i)
#pragma unroll
        for (int j = 0; j < 4; ++j) accS[i][j] = (f32x4){0.f, 0.f, 0.f, 0.f};

    const __bf16* pa = adjb + (size_t)(wl0 + rA) * 1024 + kg * 8;
    const int qf = t >> 6;          // not used; silence
    (void)qf;

    bf16x8 st[16];
    // prologue: stage half 0
#pragma unroll
    for (int i = 0; i < 16; ++i) {
        int q = i * 256 + t;
        int f = q >> 6, cm = q & 63;
        st[i] = *(const bf16x8*)(ywb + (size_t)f * 1024 + cm * 8);
    }
#pragma unroll
    for (int i = 0; i < 16; ++i) {
        int q = i * 256 + t;
        int f = q >> 6, cm = q & 63;
        *(bf16x8*)&sYW[f * 512 + ((cm ^ (f & 7)) << 3)] = st[i];
    }
    __syncthreads();
    // issue half-1 prefetch (latency hides under half-0 MFMA)
#pragma unroll
    for (int i = 0; i < 16; ++i) {
        int q = i * 256 + t;
        int f = q >> 6, cm = q & 63;
        st[i] = *(const bf16x8*)(ywb + (size_t)f * 1024 + 512 + cm * 8);
    }
    // MFMA half 0
#pragma unroll 4
    for (int ksl = 0; ksl < 16; ++ksl) {
        bf16x8 a0 = *(const bf16x8*)(pa + ksl * 32);
        bf16x8 a1 = *(const bf16x8*)(pa + 16 * 1024 + ksl * 32);
        const int ch = ((kg + ksl * 4) ^ fr) << 3;
        bf16x8 f0 = *(const bf16x8*)&sYW[(0 * 16 + rA) * 512 + ch];
        bf16x8 f1 = *(const bf16x8*)&sYW[(1 * 16 + rA) * 512 + ch];
        bf16x8 f2 = *(const bf16x8*)&sYW[(2 * 16 + rA) * 512 + ch];
        bf16x8 f3 = *(const bf16x8*)&sYW[(3 * 16 + rA) * 512 + ch];
        accS[0][0] = __builtin_amdgcn_mfma_f32_16x16x32_bf16(a0, f0, accS[0][0], 0, 0, 0);
        accS[0][1] = __builtin_amdgcn_mfma_f32_16x16x32_bf16(a0, f1, accS[0][1], 0, 0, 0);
        accS[0][2] = __builtin_amdgcn_mfma_f32_16x16x32_bf16(a0, f2, accS[0][2], 0, 0, 0);
        accS[0][3] = __builtin_amdgcn_mfma_f32_16x16x32_bf16(a0, f3, accS[0][3], 0, 0, 0);
        accS[1][0] = __builtin_amdgcn_mfma_f32_16x16x32_bf16(a1, f0, accS[1][0], 0, 0, 0);
        accS[1][1] = __builtin_amdgcn_mfma_f32_16x16x32_bf16(a1, f1, accS[1][1], 0, 0, 0);
        accS[1][2] = __builtin_amdgcn_mfma_f32_16x16x32_bf16(a1, f2, accS[1][2], 0, 0, 0);
        accS[1][3] = __builtin_amdgcn_mfma_f32_16x16x32_bf16(a1, f3, accS[1][3], 0, 0, 0);
    }
    __syncthreads();
    // write half 1
#pragma unroll
    for (int i = 0; i < 16; ++i) {
        int q = i * 256 + t;
        int f = q >> 6, cm = q & 63;
        *(bf16x8*)&sYW[f * 512 + ((cm ^ (f & 7)) << 3)] = st[i];
    }
    __syncthreads();
    // MFMA half 1
#pragma unroll 4
    for (int ksl = 0; ksl < 16; ++ksl) {
        bf16x8 a0 = *(const bf16x8*)(pa + (16 + ksl) * 32);
        bf16x8 a1 = *(const bf16x8*)(pa + 16 * 1024 + (16 + ksl) * 32);
        const int ch = ((kg + ksl * 4) ^ fr) << 3;
        bf16x8 f0 = *(const bf16x8*)&sYW[(0 * 16 + rA) * 512 + ch];
        bf16x8 f1 = *(const bf16x8*)&sYW[(1 * 16 + rA) * 512 + ch];
        bf16x8 f2 = *(const bf16x8*)&sYW[(2 * 16 + rA) * 512 + ch];
        bf16x8 f3 = *(const bf16x8*)&sYW[(3 * 16 + rA) * 512 + ch];
        accS[0][0] = __builtin_amdgcn_mfma_f32_16x16x32_bf16(a0, f0, accS[0][0], 0, 0, 0);
        accS[0][1] = __builtin_amdgcn_mfma_f32_16x16x32_bf16(a0, f1, accS[0][1], 0, 0, 0);
        accS[0][2] = __builtin_amdgcn_mfma_f32_16x16x32_bf16(a0, f2, accS[0][2], 0, 0, 0);
        accS[0][3] = __builtin_amdgcn_mfma_f32_16x16x32_bf16(a0, f3, accS[0][3], 0, 0, 0);
        accS[1][0] = __builtin_amdgcn_mfma_f32_16x16x32_bf16(a1, f0, accS[1][0], 0, 0, 0);
        accS[1][1] = __builtin_amdgcn_mfma_f32_16x16x32_bf16(a1, f1, accS[1][1], 0, 0, 0);
        accS[1][2] = __builtin_amdgcn_mfma_f32_16x16x32_bf16(a1, f2, accS[1][2], 0, 0, 0);
        accS[1][3] = __builtin_amdgcn_mfma_f32_16x16x32_bf16(a1, f3, accS[1][3], 0, 0, 0);
    }
    __syncthreads();    // protect pool reuse (sYW -> sPre)

    // dynamic path: D[l][f] = sum_c Pt[l][c] * Zwt[f][c], K=32 (c padded)
    f32x4 accD[2][4];
#pragma unroll
    for (int i = 0; i < 2; ++i)
#pragma unroll
        for (int j = 0; j < 4; ++j) accD[i][j] = (f32x4){0.f, 0.f, 0.f, 0.f};
    {
        const __bf16* qa = Ptb + (size_t)(wl0 + rA) * 32 + kg * 8;
        bf16x8 a0 = *(const bf16x8*)(qa);
        bf16x8 a1 = *(const bf16x8*)(qa + 16 * 32);
        const __bf16* qb = Zwtb + (size_t)rA * 32 + kg * 8;
        bf16x8 z0 = *(const bf16x8*)(qb + 0 * 512);
        bf16x8 z1 = *(const bf16x8*)(qb + 1 * 512);
        bf16x8 z2 = *(const bf16x8*)(qb + 2 * 512);
        bf16x8 z3 = *(const bf16x8*)(qb + 3 * 512);
        accD[0][0] = __builtin_amdgcn_mfma_f32_16x16x32_bf16(a0, z0, accD[0][0], 0, 0, 0);
        accD[0][1] = __builtin_amdgcn_mfma_f32_16x16x32_bf16(a0, z1, accD[0][1], 0, 0, 0);
        accD[0][2] = __builtin_amdgcn_mfma_f32_16x16x32_bf16(a0, z2, accD[0][2], 0, 0, 0);
        accD[0][3] = __builtin_amdgcn_mfma_f32_16x16x32_bf16(a0, z3, accD[0][3], 0, 0, 0);
        accD[1][0] = __builtin_amdgcn_mfma_f32_16x16x32_bf16(a1, z0, accD[1][0], 0, 0, 0);
        accD[1][1] = __builtin_amdgcn_mfma_f32_16x16x32_bf16(a1, z1, accD[1][1], 0, 0, 0);
        accD[1][2] = __builtin_amdgcn_mfma_f32_16x16x32_bf16(a1, z2, accD[1][2], 0, 0, 0);
        accD[1][3] = __builtin_amdgcn_mfma_f32_16x16x32_bf16(a1, z3, accD[1][3], 0, 0, 0);
    }

    // epilogue: pre = relu(D + b_g) + relu(S + b_sp) + 3*y  -> LDS (fp32, pad 68)
    float bg4[4], bs4[4];
#pragma unroll
    for (int fc = 0; fc < 4; ++fc) { bg4[fc] = b_g[fc * 16 + rA]; bs4[fc] = b_sp[fc * 16 + rA]; }
    const ushort* yb = yb16 + ((size_t)b << 16);
    const int wOff = w * 32 * 68;
#pragma unroll
    for (int lt = 0; lt < 2; ++lt) {
        int lbase = wl0 + lt * 16 + kg * 4;
        int row = lt * 16 + kg * 4;
#pragma unroll
        for (int fc = 0; fc < 4; ++fc) {
            int f = fc * 16 + rA;
            ushort4 uy = *(const ushort4*)(yb + (size_t)f * 1024 + lbase);
            const float ya[4] = {bf2f(uy.x), bf2f(uy.y), bf2f(uy.z), bf2f(uy.w)};
            f32x4 s = accS[lt][fc], d = accD[lt][fc];
            sPre[wOff + (row + 0) * 68 + f] = relu_(d[0] + bg4[fc]) + relu_(s[0] + bs4[fc]) + 3.f * ya[0];
            sPre[wOff + (row + 1) * 68 + f] = relu_(d[1] + bg4[fc]) + relu_(s[1] + bs4[fc]) + 3.f * ya[1];
            sPre[wOff + (row + 2) * 68 + f] = relu_(d[2] + bg4[fc]) + relu_(s[2] + bs4[fc]) + 3.f * ya[2];
            sPre[wOff + (row + 3) * 68 + f] = relu_(d[3] + bg4[fc]) + relu_(s[3] + bs4[fc]) + 3.f * ya[3];
        }
    }
    __syncthreads();

    // back conv: out[o][l] = relu( sum_f pre[l][f] * bwb[o][f] + bn2b[o] )
    f32x4 accO[2][4];
#pragma unroll
    for (int i = 0; i < 2; ++i)
#pragma unroll
        for (int j = 0; j < 4; ++j) accO[i][j] = (f32x4){0.f, 0.f, 0.f, 0.f};
#pragma unroll
    for (int kh = 0; kh < 2; ++kh) {
        bf16x8 af[2];
#pragma unroll
        for (int lt = 0; lt < 2; ++lt) {
            int off = wOff + (lt * 16 + rA) * 68 + kh * 32 + kg * 8;
            float4 u0 = *(const float4*)&sPre[off];
            float4 u1 = *(const float4*)&sPre[off + 4];
            bf16x8 a;
            a[0] = (__bf16)u0.x; a[1] = (__bf16)u0.y; a[2] = (__bf16)u0.z; a[3] = (__bf16)u0.w;
            a[4] = (__bf16)u1.x; a[5] = (__bf16)u1.y; a[6] = (__bf16)u1.z; a[7] = (__bf16)u1.w;
            af[lt] = a;
        }
#pragma unroll
        for (int oc = 0; oc < 4; ++oc) {
            bf16x8 bo = *(const bf16x8*)(bwb + oc * 1024 + (size_t)rA * 64 + kh * 32 + kg * 8);
            accO[0][oc] = __builtin_amdgcn_mfma_f32_16x16x32_bf16(af[0], bo, accO[0][oc], 0, 0, 0);
            accO[1][oc] = __builtin_amdgcn_mfma_f32_16x16x32_bf16(af[1], bo, accO[1][oc], 0, 0, 0);
        }
    }
    float* ob = out + ((size_t)b << 16);
#pragma unroll
    for (int oc = 0; oc < 4; ++oc) {
        float b2v = bn2b[oc * 16 + rA];
#pragma unroll
        for (int lt = 0; lt < 2; ++lt) {
            float4 ov = make_float4(accO[lt][oc][0] + b2v, accO[lt][oc][1] + b2v,
                                    accO[lt][oc][2] + b2v, accO[lt][oc][3] + b2v);
            ov.x = relu_(ov.x); ov.y = relu_(ov.y); ov.z = relu_(ov.z); ov.w = relu_(ov.w);
            *(float4*)(ob + (size_t)(oc * 16 + rA) * 1024 + wl0 + lt * 16 + kg * 4) = ov;
        }
    }
}

extern "C" void kernel_launch(void* const* d_in, const int* in_sizes, int n_in,
                              void* d_out, int out_size, void* d_ws, size_t ws_size,
                              hipStream_t stream)
{
    const float* x       = (const float*)d_in[0];
    const float* SP      = (const float*)d_in[1];
    const float* trans_w = (const float*)d_in[2];
    const float* bn1_g   = (const float*)d_in[3];
    const float* bn1_b   = (const float*)d_in[4];
    const float* w_nc    = (const float*)d_in[5];
    const float* b_nc    = (const float*)d_in[6];
    const float* w_kc    = (const float*)d_in[7];
    const float* b_kc    = (const float*)d_in[8];
    const float* w_g     = (const float*)d_in[9];
    const float* b_g     = (const float*)d_in[10];
    const float* adj     = (const float*)d_in[11];
    const float* w_sp    = (const float*)d_in[12];
    const float* b_sp    = (const float*)d_in[13];
    const float* back_w  = (const float*)d_in[14];
    const float* bn2_g   = (const float*)d_in[15];
    const float* bn2_b   = (const float*)d_in[16];
    float* out = (float*)d_out;

    float* ws = (float*)d_ws;
    float* partYN = ws;                                     // [B*16][27*64] fp32
    float* partU  = partYN + (size_t)B_ * NCHUNK * NC_ * F_;// [B*16][27*64] fp32
    ushort* Pcb  = (ushort*)(partU + (size_t)B_ * NCHUNK * NC_ * F_); // [64][27][1024] bf16
    ushort* Pt   = Pcb  + (size_t)B_ * NC_ * L_;            // [64][1024][32] bf16
    ushort* Zwt  = Pt   + (size_t)B_ * L_ * 32;             // [64][64][32] bf16
    ushort* yb16 = Zwt  + (size_t)B_ * F_ * 32;             // [64][64][1024] bf16
    ushort* ywb  = yb16 + (size_t)B_ * F_ * L_;             // [64][64][1024] bf16
    ushort* adjb = ywb  + (size_t)B_ * F_ * L_;             // [1024][1024] bf16
    ushort* bwb  = adjb + (size_t)L_ * L_;                  // [64][64] bf16

    k_softmax_prep<<<1281, 256, 0, stream>>>(SP, adj, back_w, bn2_g, Pcb, Pt, adjb, bwb);
    k_trans_mfma<<<512, 256, 0, stream>>>(x, trans_w, bn1_g, bn1_b, w_sp, yb16, ywb);
    k_yn_U_part<<<B_ * NCHUNK, 256, 0, stream>>>(yb16, Pcb, w_nc, partYN, partU);
    k_sigma_Z<<<64, 256, 0, stream>>>(partYN, partU, b_nc, w_kc, b_kc, w_g, Zwt);
    k_fused2<<<512, 256, 0, stream>>>(adjb, ywb, Pt, Zwt, yb16, b_g, b_sp, bwb, bn2_b, out);
}